// Round 11
// baseline (454.899 us; speedup 1.0000x reference)
//
#include <hip/hip_runtime.h>
#include <math.h>

// S=64 seq, B=256 atoms, N=16384, D=128, H=8, HD=16, DFF=2048, NL=6.
// R24 = R23 layers (unchanged) + s2s rebuilt for TLP. Evidence R23: s2s
// pinned at 49us with VALUBusy 5% -> not VALU-bound; 64 blocks x 8 waves
// (2/SIMD) with ~38 barriers = exposed latency. Now 1024 thr (16 waves =
// 4/SIMD): gate matvec split in half across (t, t+512) [chain 24, weights
// re-read per step from hot L2 instead of 96 persistent VGPRs], e-phase 4
// thr/atom, r-phase 8x32-atom groups, memLSTM split. lb(1024,1), LDS 74KB.

typedef _Float16 __attribute__((ext_vector_type(8))) f16x8;
typedef __attribute__((ext_vector_type(4))) float f32x4;
typedef _Float16 __attribute__((ext_vector_type(2))) h16x2;

__device__ __forceinline__ unsigned short f2h(float f) {
  union { _Float16 h; unsigned short s; } x; x.h = (_Float16)f; return x.s;
}
__device__ __forceinline__ float h2f(unsigned short u) {
  union { unsigned short s; _Float16 h; } x; x.s = u; return (float)x.h;
}
__device__ __forceinline__ unsigned packh(float a, float b) {
  return (unsigned)f2h(a) | ((unsigned)f2h(b) << 16);
}
__device__ __forceinline__ uint2 pk4(float a, float b, float c, float d) {
  return make_uint2(packh(a, b), packh(c, d));
}
__device__ __forceinline__ float hlo(unsigned u) {
  union { unsigned short s; _Float16 h; } x; x.s = (unsigned short)(u & 0xffff);
  return (float)x.h;
}
__device__ __forceinline__ float hhi(unsigned u) {
  union { unsigned short s; _Float16 h; } x; x.s = (unsigned short)(u >> 16);
  return (float)x.h;
}
__device__ __forceinline__ float fdot2u(unsigned a, unsigned b, float c) {
#if __has_builtin(__builtin_amdgcn_fdot2)
  union U { unsigned u; h16x2 h; };
  U x, y; x.u = a; y.u = b;
  return __builtin_amdgcn_fdot2(x.h, y.h, c, false);
#else
  return c + hlo(a) * hlo(b) + hhi(a) * hhi(b);
#endif
}
// fast hardware transcendentals (v_exp_f32)
__device__ __forceinline__ float fexp(float x) { return __expf(x); }
__device__ __forceinline__ float sigf(float x) {
  return 1.f / (1.f + __expf(-x));
}
__device__ __forceinline__ float ftanh(float x) {
  float e = __expf(2.f * x);
  return 1.f - 2.f / (e + 1.f);
}

// async 16B global->LDS; LDS base wave-uniform (+ lane*16 implicit).
__device__ __forceinline__ void gl2lds16(const void* g, void* l) {
  __builtin_amdgcn_global_load_lds(
      (const __attribute__((address_space(1))) unsigned int*)g,
      (__attribute__((address_space(3))) unsigned int*)l, 16, 0, 0);
}

// ---------------------------------------------------------------------------
// weight conversion: everything -> f16, frag-major (see R14 comment).
// ---------------------------------------------------------------------------
__global__ __launch_bounds__(256) void convw_kernel(
    const float* __restrict__ aiw, const float* __restrict__ aow,
    const float* __restrict__ w1, const float* __restrict__ w2,
    const float* __restrict__ wih, const float* __restrict__ whh,
    const float* __restrict__ mwih,
    unsigned short* __restrict__ o0, unsigned short* __restrict__ o1,
    unsigned short* __restrict__ o2, unsigned short* __restrict__ o3,
    unsigned short* __restrict__ o4, unsigned short* __restrict__ o5,
    unsigned short* __restrict__ o6) {
  int i = blockIdx.x * 256 + threadIdx.x;
  if (i < 294912) {
    int l = i / 49152, o = i % 49152;
    int j = o & 7, fr = (o >> 3) & 15, fq = (o >> 7) & 3, ks = (o >> 9) & 3,
        rb = o >> 11;
    o0[i] = f2h(aiw[l * 49152 + (rb * 16 + fr) * 128 + ks * 32 + fq * 8 + j]);
  } else if (i < 393216) {
    int ii = i - 294912;
    int l = ii / 16384, o = ii % 16384;
    int j = o & 7, fr = (o >> 3) & 15, fq = (o >> 7) & 3, ks = (o >> 9) & 3,
        rb = o >> 11;
    o1[ii] = f2h(aow[l * 16384 + (rb * 16 + fr) * 128 + ks * 32 + fq * 8 + j]);
  } else if (i < 1966080) {
    int ii = i - 393216;
    int l = ii >> 18, o = ii & 262143;
    int j = o & 7, fr = (o >> 3) & 15, fq = (o >> 7) & 3, ks = (o >> 9) & 3,
        rb = o >> 11;
    o2[ii] = f2h(w1[l * 262144 + (rb * 16 + fr) * 128 + ks * 32 + fq * 8 + j]);
  } else if (i < 3538944) {
    int ii = i - 1966080;
    int l = ii >> 18, o = ii & 262143;
    int j = o & 7, fr = (o >> 3) & 15, fq = (o >> 7) & 3, ks = (o >> 9) & 63,
        rb = o >> 15;
    o3[ii] = f2h(w2[l * 262144 + (rb * 16 + fr) * 2048 + ks * 32 + fq * 8 + j]);
  } else if (i < 3670016) {
    int j = i - 3538944; o4[j] = f2h(wih[j]);
  } else if (i < 3735552) {
    int j = i - 3670016; o5[j] = f2h(whh[j]);
  } else {
    int j = i - 3735552; o6[j] = f2h(mwih[j]);
  }
}

// ---------------------------------------------------------------------------
// lin0: x = relu(data @ w^T + b), writes fp32 x and f16 xb
// ---------------------------------------------------------------------------
__global__ __launch_bounds__(256) void lin0_kernel(
    const float* __restrict__ data, const float* __restrict__ w,
    const float* __restrict__ b, float* __restrict__ x,
    unsigned short* __restrict__ xb) {
  int i = blockIdx.x * 256 + threadIdx.x;
  int n = i >> 7, d = i & 127;
  float v = b[d] + data[n * 3 + 0] * w[d * 3 + 0]
                 + data[n * 3 + 1] * w[d * 3 + 1]
                 + data[n * 3 + 2] * w[d * 3 + 2];
  v = fmaxf(v, 0.0f);
  x[i] = v;
  xb[i] = f2h(v);
}

// ---------------------------------------------------------------------------
// Fused transformer LAYER: block = (atom b, s-half), 256 threads, 4 waves.
// ---------------------------------------------------------------------------
__global__ __launch_bounds__(256, 2) void layer_kernel(
    const unsigned short* __restrict__ xbg,
    const unsigned short* __restrict__ wqkv, const float* __restrict__ bqkv,
    const unsigned short* __restrict__ wout, const float* __restrict__ bout,
    const float* __restrict__ ln1g, const float* __restrict__ ln1b,
    const unsigned short* __restrict__ w1, const float* __restrict__ b1,
    const unsigned short* __restrict__ w2, const float* __restrict__ b2,
    const float* __restrict__ ln2g, const float* __restrict__ ln2b,
    float* __restrict__ xio, unsigned short* __restrict__ xbo) {
  // shorts: Xs[0,8192) Ks[8192,16384) VT[16384,24576) Qs[24576,28672)
  __shared__ __align__(16) unsigned short SM[28672];
  __shared__ float psum[4][32], psq[4][32];
  __shared__ float2 stats[32];
  __shared__ __align__(16) uint4 zchunk;

  unsigned short* Xs = SM;             // x input -> P slots -> Hs buf0
  unsigned short* Ks = SM + 8192;      // K [s][feat] -> Hs buf1
  unsigned short* VT = SM + 16384;     // V^T [feat][s] -> AOs
  unsigned short* AOs = SM + 16384;    // AO [s][feat] 32x128
  unsigned short* Qs = SM + 24576;     // own-half Q [s][feat] 32x128 -> Xn
  unsigned short* Xn = SM + 24576;

  int tid = threadIdx.x, w = tid >> 6, lane = tid & 63;
  int b = blockIdx.x >> 1, half = blockIdx.x & 1;
  int r4 = lane >> 4, cs = lane & 15;
  int fr = lane & 15, fq = lane >> 4;

  if (tid == 0) zchunk = make_uint4(0u, 0u, 0u, 0u);

  // ---- phase 0: stage full x tile (rows 0..63) ----
#pragma unroll
  for (int i = 0; i < 4; i++) {
    int issue = w * 4 + i;
    int row = issue * 4 + r4;
    int g = cs ^ (row & 7);
    gl2lds16(xbg + (size_t)(row * 256 + b) * 128 + g * 8,
             (char*)Xs + issue * 1024);
  }
  // preload pass-Q weights (8 frags = 32 VGPR) while staging is in flight
  f16x8 wq[4][2];
#pragma unroll
  for (int ks = 0; ks < 4; ks++)
#pragma unroll
    for (int ni = 0; ni < 2; ni++)
      wq[ks][ni] = *(const f16x8*)(wqkv + (size_t)(w * 2 + ni) * 2048 +
                                   ks * 512 + fq * 128 + fr * 8);
  __syncthreads();

  // ---- phase 1: QKV, 3 passes, ONE barrier ----
  // Pass Q (SWAPPED: A=W, B=x): own 32 rows. D[qfeat][s] -> store Qs[s][qfeat]
  {
    f32x4 acc[2][2];
#pragma unroll
    for (int i = 0; i < 2; i++)
#pragma unroll
      for (int j = 0; j < 2; j++) acc[i][j] = (f32x4){0.f, 0.f, 0.f, 0.f};
#pragma unroll
    for (int ks = 0; ks < 4; ks++) {
      f16x8 bx[2];
#pragma unroll
      for (int mi2 = 0; mi2 < 2; mi2++) {
        int row = half * 32 + mi2 * 16 + fr;
        int kq = (ks * 4 + fq) ^ (row & 7);
        bx[mi2] = *(const f16x8*)(Xs + row * 128 + kq * 8);
      }
#pragma unroll
      for (int mi2 = 0; mi2 < 2; mi2++)
#pragma unroll
        for (int ni = 0; ni < 2; ni++)
          acc[mi2][ni] = __builtin_amdgcn_mfma_f32_16x16x32_f16(
              wq[ks][ni], bx[mi2], acc[mi2][ni], 0, 0, 0);
    }
#pragma unroll
    for (int ni = 0; ni < 2; ni++) {
      int fb = (w * 2 + ni) * 16 + fq * 4;
      float4 bv = *(const float4*)&bqkv[fb];
#pragma unroll
      for (int mi2 = 0; mi2 < 2; mi2++) {
        int srow = mi2 * 16 + fr;  // local 0..31
        *(uint2*)(Qs + srow * 128 + (((fb >> 3) ^ (srow & 7)) << 3) +
                  (fb & 7)) =
            pk4(acc[mi2][ni][0] + bv.x, acc[mi2][ni][1] + bv.y,
                acc[mi2][ni][2] + bv.z, acc[mi2][ni][3] + bv.w);
      }
    }
  }
  // Pass K (SWAPPED): full 64 rows. D[kfeat][s] -> store Ks[s][kfeat]
  {
    // preload all 8 K-weight frags
    f16x8 wk[4][2];
#pragma unroll
    for (int ks = 0; ks < 4; ks++)
#pragma unroll
      for (int ni = 0; ni < 2; ni++)
        wk[ks][ni] = *(const f16x8*)(wqkv + (size_t)(8 + w * 2 + ni) * 2048 +
                                     ks * 512 + fq * 128 + fr * 8);
    f32x4 acc[4][2];
#pragma unroll
    for (int i = 0; i < 4; i++)
#pragma unroll
      for (int j = 0; j < 2; j++) acc[i][j] = (f32x4){0.f, 0.f, 0.f, 0.f};
#pragma unroll
    for (int ks = 0; ks < 4; ks++) {
      f16x8 bx[4];
#pragma unroll
      for (int mi = 0; mi < 4; mi++) {
        int row = mi * 16 + fr;
        int kq = (ks * 4 + fq) ^ (row & 7);
        bx[mi] = *(const f16x8*)(Xs + row * 128 + kq * 8);
      }
#pragma unroll
      for (int mi = 0; mi < 4; mi++)
#pragma unroll
        for (int ni = 0; ni < 2; ni++)
          acc[mi][ni] = __builtin_amdgcn_mfma_f32_16x16x32_f16(
              wk[ks][ni], bx[mi], acc[mi][ni], 0, 0, 0);
    }
#pragma unroll
    for (int ni = 0; ni < 2; ni++) {
      int fb = (w * 2 + ni) * 16 + fq * 4;
      float4 bv = *(const float4*)&bqkv[128 + fb];
#pragma unroll
      for (int mi = 0; mi < 4; mi++) {
        int srow = mi * 16 + fr;
        *(uint2*)(Ks + srow * 128 + (((fb >> 3) ^ (srow & 7)) << 3) +
                  (fb & 7)) =
            pk4(acc[mi][ni][0] + bv.x, acc[mi][ni][1] + bv.y,
                acc[mi][ni][2] + bv.z, acc[mi][ni][3] + bv.w);
      }
    }
  }
  // Pass V (UNSWAPPED: A=x, B=W): D[s][vfeat] -> store VT[vfeat][s] packed
  {
    // preload all 8 V-weight frags
    f16x8 wv[4][2];
#pragma unroll
    for (int ks = 0; ks < 4; ks++)
#pragma unroll
      for (int ni = 0; ni < 2; ni++)
        wv[ks][ni] = *(const f16x8*)(wqkv + (size_t)(16 + w * 2 + ni) * 2048 +
                                     ks * 512 + fq * 128 + fr * 8);
    f32x4 acc[4][2];
#pragma unroll
    for (int i = 0; i < 4; i++)
#pragma unroll
      for (int j = 0; j < 2; j++) acc[i][j] = (f32x4){0.f, 0.f, 0.f, 0.f};
#pragma unroll
    for (int ks = 0; ks < 4; ks++) {
      f16x8 ax[4];
#pragma unroll
      for (int mi = 0; mi < 4; mi++) {
        int row = mi * 16 + fr;
        int kq = (ks * 4 + fq) ^ (row & 7);
        ax[mi] = *(const f16x8*)(Xs + row * 128 + kq * 8);
      }
#pragma unroll
      for (int mi = 0; mi < 4; mi++)
#pragma unroll
        for (int ni = 0; ni < 2; ni++)
          acc[mi][ni] = __builtin_amdgcn_mfma_f32_16x16x32_f16(
              ax[mi], wv[ks][ni], acc[mi][ni], 0, 0, 0);
    }
#pragma unroll
    for (int ni = 0; ni < 2; ni++) {
      int feat = (w * 2 + ni) * 16 + fr;
      float bv = bqkv[256 + feat];
#pragma unroll
      for (int mi = 0; mi < 4; mi++) {
        int sb = mi * 16 + fq * 4;
        *(uint2*)(VT + feat * 64 + (((sb >> 3) ^ (feat & 7)) << 3) +
                  (sb & 7)) =
            pk4(acc[mi][ni][0] + bv, acc[mi][ni][1] + bv,
                acc[mi][ni][2] + bv, acc[mi][ni][3] + bv);
      }
    }
  }
  // preload Wout frags (8 = 32 VGPR) -- consumed in phase 4, issued here so
  // L2 latency hides under the attention phase.
  f16x8 wo[4][2];
#pragma unroll
  for (int ks = 0; ks < 4; ks++)
#pragma unroll
    for (int ni = 0; ni < 2; ni++)
      wo[ks][ni] = *(const f16x8*)(wout + (size_t)(w * 2 + ni) * 2048 +
                                   ks * 512 + fq * 128 + fr * 8);
  __syncthreads();  // QKV published; Xs reads done -> Xs reusable as P slots

  // ---- attention: wave w -> heads {2w, 2w+1}, own 32 rows; P in Xs ----
  f32x4 po[2][2];
#pragma unroll
  for (int i = 0; i < 2; i++)
#pragma unroll
    for (int j = 0; j < 2; j++) po[i][j] = (f32x4){0.f, 0.f, 0.f, 0.f};
  {
    unsigned short* Pb = Xs + w * 2048;  // 4KB wave-private slot
#pragma unroll
    for (int hi = 0; hi < 2; hi++) {
      int h = w * 2 + hi;
      f16x8 afH[2], bfH[4];
#pragma unroll
      for (int mi2 = 0; mi2 < 2; mi2++) {
        int qrow = mi2 * 16 + fr;  // local 0..31
        const unsigned short* pa =
            (fq < 2) ? (Qs + qrow * 128 + (((h * 2 + fq) ^ (qrow & 7)) << 3))
                     : (const unsigned short*)&zchunk;
        afH[mi2] = *(const f16x8*)pa;
      }
#pragma unroll
      for (int ti = 0; ti < 4; ti++) {
        int trow = ti * 16 + fr;
        const unsigned short* pb =
            (fq < 2) ? (Ks + trow * 128 + (((h * 2 + fq) ^ (trow & 7)) << 3))
                     : (const unsigned short*)&zchunk;
        bfH[ti] = *(const f16x8*)pb;
      }
      f32x4 sc[2][4];
#pragma unroll
      for (int i = 0; i < 2; i++)
#pragma unroll
        for (int j = 0; j < 4; j++) sc[i][j] = (f32x4){0.f, 0.f, 0.f, 0.f};
#pragma unroll
      for (int mi2 = 0; mi2 < 2; mi2++)
#pragma unroll
        for (int ti = 0; ti < 4; ti++)
          sc[mi2][ti] = __builtin_amdgcn_mfma_f32_16x16x32_f16(
              afH[mi2], bfH[ti], sc[mi2][ti], 0, 0, 0);
#pragma unroll
      for (int mi2 = 0; mi2 < 2; mi2++) {
#pragma unroll
        for (int r = 0; r < 4; r++) {
          float m = -1e30f;
#pragma unroll
          for (int ti = 0; ti < 4; ti++) m = fmaxf(m, sc[mi2][ti][r]);
          m = fmaxf(m, __shfl_xor(m, 1, 64));
          m = fmaxf(m, __shfl_xor(m, 2, 64));
          m = fmaxf(m, __shfl_xor(m, 4, 64));
          m = fmaxf(m, __shfl_xor(m, 8, 64));
          m *= 0.25f;
          float ss = 0.f;
#pragma unroll
          for (int ti = 0; ti < 4; ti++) {
            float p = fexp(sc[mi2][ti][r] * 0.25f - m);
            sc[mi2][ti][r] = p;
            ss += p;
          }
          ss += __shfl_xor(ss, 1, 64);
          ss += __shfl_xor(ss, 2, 64);
          ss += __shfl_xor(ss, 4, 64);
          ss += __shfl_xor(ss, 8, 64);
          float inv = 1.f / ss;
          int prow = mi2 * 16 + fq * 4 + r;  // local 0..31
#pragma unroll
          for (int ti = 0; ti < 4; ti++) {
            int t = ti * 16 + fr;
            Pb[prow * 64 + (((t >> 3) ^ (prow & 7)) << 3) + (t & 7)] =
                f2h(sc[mi2][ti][r] * inv);
          }
        }
      }
      // PV SWAPPED: A=VT frag, B=P frag -> D[vfeat][s]
#pragma unroll
      for (int ks2 = 0; ks2 < 2; ks2++) {
        f16x8 bp[2], avt;
#pragma unroll
        for (int si2 = 0; si2 < 2; si2++) {
          int prow = si2 * 16 + fr;
          int kq = (ks2 * 4 + fq) ^ (prow & 7);
          bp[si2] = *(const f16x8*)(Pb + prow * 64 + kq * 8);
        }
        {
          int vrow = h * 16 + fr;
          int kq = (ks2 * 4 + fq) ^ (vrow & 7);
          avt = *(const f16x8*)(VT + vrow * 64 + kq * 8);
        }
#pragma unroll
        for (int si2 = 0; si2 < 2; si2++)
          po[hi][si2] = __builtin_amdgcn_mfma_f32_16x16x32_f16(
              avt, bp[si2], po[hi][si2], 0, 0, 0);
      }
    }
  }
  __syncthreads();  // all PV reads of VT done -> VT reusable as AOs
  // AO store: lane holds 4 consecutive vfeat at fixed s -> b64
#pragma unroll
  for (int hi = 0; hi < 2; hi++) {
    int fb = (w * 2 + hi) * 16 + fq * 4;
#pragma unroll
    for (int si2 = 0; si2 < 2; si2++) {
      int srow = si2 * 16 + fr;
      *(uint2*)(AOs + srow * 128 + (((fb >> 3) ^ (srow & 7)) << 3) +
                (fb & 7)) =
          pk4(po[hi][si2][0], po[hi][si2][1], po[hi][si2][2], po[hi][si2][3]);
    }
  }
  __syncthreads();  // AO published

  // ---- phase 4 (SWAPPED): v = x + ao @ Wout^T + bias ; LN1 -> Xn ----
  {
    f32x4 acc[2][2];
#pragma unroll
    for (int i = 0; i < 2; i++)
#pragma unroll
      for (int j = 0; j < 2; j++) acc[i][j] = (f32x4){0.f, 0.f, 0.f, 0.f};
#pragma unroll
    for (int ks = 0; ks < 4; ks++) {
      f16x8 bao[2];
#pragma unroll
      for (int mi2 = 0; mi2 < 2; mi2++) {
        int row = mi2 * 16 + fr;
        int kq = (ks * 4 + fq) ^ (row & 7);
        bao[mi2] = *(const f16x8*)(AOs + row * 128 + kq * 8);
      }
#pragma unroll
      for (int mi2 = 0; mi2 < 2; mi2++)
#pragma unroll
        for (int ni = 0; ni < 2; ni++)
          acc[mi2][ni] = __builtin_amdgcn_mfma_f32_16x16x32_f16(
              wo[ks][ni], bao[mi2], acc[mi2][ni], 0, 0, 0);
    }
    // lane: s = mi2*16+fr (local), feats = (w*2+ni)*16 + fq*4 + r
    float v4[2][2][4];  // [ni][mi2][r]
    float psA[2] = {0.f, 0.f}, psQ[2] = {0.f, 0.f};
#pragma unroll
    for (int ni = 0; ni < 2; ni++) {
      int fb = (w * 2 + ni) * 16 + fq * 4;
      float4 bv = *(const float4*)&bout[fb];
#pragma unroll
      for (int mi2 = 0; mi2 < 2; mi2++) {
        int rowg = half * 32 + mi2 * 16 + fr;
        float4 rs = *(const float4*)&xio[(size_t)(rowg * 256 + b) * 128 + fb];
        float t0 = acc[mi2][ni][0] + bv.x + rs.x;
        float t1 = acc[mi2][ni][1] + bv.y + rs.y;
        float t2 = acc[mi2][ni][2] + bv.z + rs.z;
        float t3 = acc[mi2][ni][3] + bv.w + rs.w;
        v4[ni][mi2][0] = t0; v4[ni][mi2][1] = t1;
        v4[ni][mi2][2] = t2; v4[ni][mi2][3] = t3;
        psA[mi2] += (t0 + t1) + (t2 + t3);
        psQ[mi2] += (t0 * t0 + t1 * t1) + (t2 * t2 + t3 * t3);
      }
    }
#pragma unroll
    for (int mi2 = 0; mi2 < 2; mi2++) {
      psA[mi2] += __shfl_xor(psA[mi2], 16, 64);
      psA[mi2] += __shfl_xor(psA[mi2], 32, 64);
      psQ[mi2] += __shfl_xor(psQ[mi2], 16, 64);
      psQ[mi2] += __shfl_xor(psQ[mi2], 32, 64);
    }
    if (fq == 0) {
#pragma unroll
      for (int mi2 = 0; mi2 < 2; mi2++) {
        psum[w][mi2 * 16 + fr] = psA[mi2];
        psq[w][mi2 * 16 + fr] = psQ[mi2];
      }
    }
    __syncthreads();  // A
    if (tid < 32) {
      float S = 0.f, Q = 0.f;
#pragma unroll
      for (int ww = 0; ww < 4; ww++) { S += psum[ww][tid]; Q += psq[ww][tid]; }
      float m = S * (1.f / 128.f);
      float var = Q * (1.f / 128.f) - m * m;
      stats[tid] = make_float2(m, rsqrtf(var + 1e-5f));
    }
    __syncthreads();  // B
#pragma unroll
    for (int ni = 0; ni < 2; ni++) {
      int fb = (w * 2 + ni) * 16 + fq * 4;
      float4 g4 = *(const float4*)&ln1g[fb];
      float4 b4 = *(const float4*)&ln1b[fb];
#pragma unroll
      for (int mi2 = 0; mi2 < 2; mi2++) {
        int srow = mi2 * 16 + fr;
        float2 st = stats[srow];
        float y0 = (v4[ni][mi2][0] - st.x) * st.y * g4.x + b4.x;
        float y1 = (v4[ni][mi2][1] - st.x) * st.y * g4.y + b4.y;
        float y2 = (v4[ni][mi2][2] - st.x) * st.y * g4.z + b4.z;
        float y3 = (v4[ni][mi2][3] - st.x) * st.y * g4.w + b4.w;
        *(uint2*)(Xn + srow * 128 + (((fb >> 3) ^ (srow & 7)) << 3) +
                  (fb & 7)) = pk4(y0, y1, y2, y3);
      }
    }
  }
  __syncthreads();  // C: LN1 out published; Xs+Ks dead -> Hs dbuf (2x16KB)

  // hoisted FFN x fragments (B-operand; local 32 rows)
  f16x8 xfragF[4][2];
#pragma unroll
  for (int ks = 0; ks < 4; ks++)
#pragma unroll
    for (int mi2 = 0; mi2 < 2; mi2++) {
      int rowl = mi2 * 16 + fr;
      int kq = (ks * 4 + fq) ^ (rowl & 7);
      xfragF[ks][mi2] = *(const f16x8*)(Xn + rowl * 128 + kq * 8);
    }

  // ---- FFN (SWAPPED): 8 chunks x 256 hidden. H stored [s][hcol] packed.
  f32x4 acc2[2][2];
#pragma unroll
  for (int i = 0; i < 2; i++)
#pragma unroll
    for (int j = 0; j < 2; j++) acc2[i][j] = (f32x4){0.f, 0.f, 0.f, 0.f};

  for (int c = 0; c < 8; c++) {
    unsigned short* Hcur = SM + (c & 1) * 8192;
    // preload full ff1 weight set for this chunk (16 frags = 64 VGPR)
    f16x8 aw1[4][4];
#pragma unroll
    for (int ks = 0; ks < 4; ks++)
#pragma unroll
      for (int ni = 0; ni < 4; ni++)
        aw1[ks][ni] = *(const f16x8*)(w1 + (size_t)(c * 16 + w * 4 + ni) *
                                              2048 +
                                      ks * 512 + fq * 128 + fr * 8);
    f32x4 acc1[2][4];
#pragma unroll
    for (int i = 0; i < 2; i++)
#pragma unroll
      for (int j = 0; j < 4; j++) acc1[i][j] = (f32x4){0.f, 0.f, 0.f, 0.f};
#pragma unroll
    for (int ks = 0; ks < 4; ks++)
#pragma unroll
      for (int mi2 = 0; mi2 < 2; mi2++)
#pragma unroll
        for (int ni = 0; ni < 4; ni++)
          acc1[mi2][ni] = __builtin_amdgcn_mfma_f32_16x16x32_f16(
              aw1[ks][ni], xfragF[ks][mi2], acc1[mi2][ni], 0, 0, 0);
#pragma unroll
    for (int ni = 0; ni < 4; ni++) {
      int hb = (w * 4 + ni) * 16 + fq * 4;  // 0..255
      float4 bv = *(const float4*)&b1[c * 256 + hb];
#pragma unroll
      for (int mi2 = 0; mi2 < 2; mi2++) {
        int srow = mi2 * 16 + fr;
        *(uint2*)(Hcur + srow * 256 + (((hb >> 3) ^ (srow & 7)) << 3) +
                  (hb & 7)) =
            pk4(fmaxf(acc1[mi2][ni][0] + bv.x, 0.f),
                fmaxf(acc1[mi2][ni][1] + bv.y, 0.f),
                fmaxf(acc1[mi2][ni][2] + bv.z, 0.f),
                fmaxf(acc1[mi2][ni][3] + bv.w, 0.f));
      }
    }
    // preload full ff2 weight set BEFORE the barrier (16 frags = 64 VGPR);
    // their ~200cy L2 latency hides under the barrier wait.
    f16x8 aw2[8][2];
#pragma unroll
    for (int ks2 = 0; ks2 < 8; ks2++)
#pragma unroll
      for (int ni = 0; ni < 2; ni++)
        aw2[ks2][ni] = *(const f16x8*)(w2 + (size_t)(w * 2 + ni) * 32768 +
                                       (c * 8 + ks2) * 512 + fq * 128 +
                                       fr * 8);
    __syncthreads();  // Hcur visible; dbuf -> 1 barrier/chunk
#pragma unroll
    for (int ks2 = 0; ks2 < 8; ks2++) {
      f16x8 bh[2];
#pragma unroll
      for (int mi2 = 0; mi2 < 2; mi2++) {
        int row = mi2 * 16 + fr;
        int kq = (ks2 * 4 + fq) ^ (row & 7);
        bh[mi2] = *(const f16x8*)(Hcur + row * 256 + kq * 8);
      }
#pragma unroll
      for (int mi2 = 0; mi2 < 2; mi2++)
#pragma unroll
        for (int ni = 0; ni < 2; ni++)
          acc2[mi2][ni] = __builtin_amdgcn_mfma_f32_16x16x32_f16(
              aw2[ks2][ni], bh[mi2], acc2[mi2][ni], 0, 0, 0);
    }
  }

  // ---- FFN epilogue: +b2 + residual (Xn), LN2, write global ----
  {
    float v4[2][2][4];  // [ni][mi2][r]
    float psA[2] = {0.f, 0.f}, psQ[2] = {0.f, 0.f};
#pragma unroll
    for (int ni = 0; ni < 2; ni++) {
      int fb = (w * 2 + ni) * 16 + fq * 4;
      float4 bv = *(const float4*)&b2[fb];
#pragma unroll
      for (int mi2 = 0; mi2 < 2; mi2++) {
        int srow = mi2 * 16 + fr;
        uint2 rz = *(const uint2*)(Xn + srow * 128 +
                                   (((fb >> 3) ^ (srow & 7)) << 3) + (fb & 7));
        float t0 = acc2[mi2][ni][0] + bv.x + hlo(rz.x);
        float t1 = acc2[mi2][ni][1] + bv.y + hhi(rz.x);
        float t2 = acc2[mi2][ni][2] + bv.z + hlo(rz.y);
        float t3 = acc2[mi2][ni][3] + bv.w + hhi(rz.y);
        v4[ni][mi2][0] = t0; v4[ni][mi2][1] = t1;
        v4[ni][mi2][2] = t2; v4[ni][mi2][3] = t3;
        psA[mi2] += (t0 + t1) + (t2 + t3);
        psQ[mi2] += (t0 * t0 + t1 * t1) + (t2 * t2 + t3 * t3);
      }
    }
#pragma unroll
    for (int mi2 = 0; mi2 < 2; mi2++) {
      psA[mi2] += __shfl_xor(psA[mi2], 16, 64);
      psA[mi2] += __shfl_xor(psA[mi2], 32, 64);
      psQ[mi2] += __shfl_xor(psQ[mi2], 16, 64);
      psQ[mi2] += __shfl_xor(psQ[mi2], 32, 64);
    }
    if (fq == 0) {
#pragma unroll
      for (int mi2 = 0; mi2 < 2; mi2++) {
        psum[w][mi2 * 16 + fr] = psA[mi2];
        psq[w][mi2 * 16 + fr] = psQ[mi2];
      }
    }
    __syncthreads();
    if (tid < 32) {
      float S = 0.f, Q = 0.f;
#pragma unroll
      for (int ww = 0; ww < 4; ww++) { S += psum[ww][tid]; Q += psq[ww][tid]; }
      float m = S * (1.f / 128.f);
      float var = Q * (1.f / 128.f) - m * m;
      stats[tid] = make_float2(m, rsqrtf(var + 1e-5f));
    }
    __syncthreads();
#pragma unroll
    for (int ni = 0; ni < 2; ni++) {
      int fb = (w * 2 + ni) * 16 + fq * 4;
      float4 g4 = *(const float4*)&ln2g[fb];
      float4 b4 = *(const float4*)&ln2b[fb];
#pragma unroll
      for (int mi2 = 0; mi2 < 2; mi2++) {
        int srow = mi2 * 16 + fr;
        float2 st = stats[srow];
        float y0 = (v4[ni][mi2][0] - st.x) * st.y * g4.x + b4.x;
        float y1 = (v4[ni][mi2][1] - st.x) * st.y * g4.y + b4.y;
        float y2 = (v4[ni][mi2][2] - st.x) * st.y * g4.z + b4.z;
        float y3 = (v4[ni][mi2][3] - st.x) * st.y * g4.w + b4.w;
        size_t o = (size_t)((half * 32 + srow) * 256 + b) * 128 + fb;
        *(float4*)&xio[o] = make_float4(y0, y1, y2, y3);
        *(uint2*)&xbo[o] = pk4(y0, y1, y2, y3);
      }
    }
  }
}

// ---------------------------------------------------------------------------
// Set2Set (6 steps) + memory LSTM + lin1 + lin3. One 1024-thread block per
// segment (16 waves = 4/SIMD). Gate matvec split across (t, t+512); weights
// re-read per step from hot L2 (no 96-VGPR persistence). e-phase 4 thr/atom;
// r-phase 8 groups x 32 atoms.
// ---------------------------------------------------------------------------
__global__ __launch_bounds__(1024, 1) void s2s_kernel(
    const unsigned short* __restrict__ xb,
    const unsigned short* __restrict__ wihh,
    const unsigned short* __restrict__ whhh,
    const float* __restrict__ bih, const float* __restrict__ bhh,
    const unsigned short* __restrict__ mwihh,
    const float* __restrict__ mbih, const float* __restrict__ mbhh,
    const float* __restrict__ l1w, const float* __restrict__ l1b,
    const float* __restrict__ l3w, const float* __restrict__ l3b,
    float* __restrict__ out) {
  __shared__ __align__(16) unsigned xl[256 * 65];
  __shared__ __align__(16) unsigned qu[128];
  __shared__ __align__(16) float cst[128];
  __shared__ __align__(16) float gates[1024];
  __shared__ __align__(16) float red[256];
  __shared__ __align__(16) float aw[256];
  int s = blockIdx.x, t = threadIdx.x, lane = t & 63, w = t >> 6;
  int t0 = t & 511, hi2 = t >> 9;

  // stage x: 256 atoms x 128 dims f16 = 4096 uint4
  const uint4* xs4 = (const uint4*)(xb + (size_t)s * 32768);
#pragma unroll
  for (int it = 0; it < 4; it++) {
    int f = it * 1024 + t;
    uint4 v = xs4[f];
    int n = f >> 4, jc = (f & 15) * 4;
    unsigned* dst = xl + n * 65 + jc;
    dst[0] = v.x; dst[1] = v.y; dst[2] = v.z; dst[3] = v.w;
  }
  if (t < 128) cst[t] = 0.f;
  __syncthreads();

  const uint4* q4 = (const uint4*)qu;
  float bsum = (hi2 == 0) ? (bih[t0] + bhh[t0]) : 0.f;
  // per-thread weight pointers (half-row each); L2-hot, reloaded per step
  const uint4* wp = ((const uint4*)(wihh + (size_t)t0 * 256)) + hi2 * 16;
  const uint4* up = ((const uint4*)(whhh + (size_t)t0 * 128)) + hi2 * 8;

  for (int step = 0; step < 6; step++) {
    if (step > 0) {
      float a0 = 0.f, a1 = 0.f, a2 = 0.f, a3 = 0.f;
#pragma unroll
      for (int i = 0; i < 16; i++) {
        uint4 wv = wp[i], qv = q4[hi2 * 16 + i];
        a0 = fdot2u(wv.x, qv.x, a0);
        a1 = fdot2u(wv.y, qv.y, a1);
        a2 = fdot2u(wv.z, qv.z, a2);
        a3 = fdot2u(wv.w, qv.w, a3);
      }
#pragma unroll
      for (int i = 0; i < 8; i++) {
        uint4 uv = up[i], qv = q4[hi2 * 8 + i];
        a0 = fdot2u(uv.x, qv.x, a0);
        a1 = fdot2u(uv.y, qv.y, a1);
        a2 = fdot2u(uv.z, qv.z, a2);
        a3 = fdot2u(uv.w, qv.w, a3);
      }
      gates[t] = bsum + ((a0 + a1) + (a2 + a3));
    } else {
      gates[t] = bsum;
    }
    __syncthreads();
    if (t < 128) {
      float g0 = gates[t] + gates[512 + t];
      float g1 = gates[128 + t] + gates[640 + t];
      float g2 = gates[256 + t] + gates[768 + t];
      float g3 = gates[384 + t] + gates[896 + t];
      float ig = sigf(g0), fg = sigf(g1);
      float gg = ftanh(g2), og = sigf(g3);
      float cn = fg * cst[t] + ig * gg;
      cst[t] = cn;
      float hn = og * ftanh(cn);
      float hp = __shfl_xor(hn, 1, 64);
      if ((t & 1) == 0) qu[t >> 1] = packh(hn, hp);
    }
    __syncthreads();
    if (step > 0) {
      // e-phase: 4 threads per atom, 16-dim (8 uint) segments
      int n = t >> 2, sub = t & 3;
      const unsigned* xr = xl + n * 65 + sub * 16;
      float e0 = 0.f, e1 = 0.f;
#pragma unroll
      for (int i = 0; i < 16; i += 2) {
        e0 = fdot2u(xr[i], qu[sub * 16 + i], e0);
        e1 = fdot2u(xr[i + 1], qu[sub * 16 + i + 1], e1);
      }
      float e = e0 + e1;
      e += __shfl_xor(e, 1, 64);
      e += __shfl_xor(e, 2, 64);
      if (sub == 0) red[n] = e;
      __syncthreads();
      float v0 = red[lane], v1 = red[64 + lane];
      float v2 = red[128 + lane], v3 = red[192 + lane];
      float m = fmaxf(fmaxf(v0, v1), fmaxf(v2, v3));
#pragma unroll
      for (int d = 1; d < 64; d <<= 1) m = fmaxf(m, __shfl_xor(m, d, 64));
      float p0 = fexp(v0 - m), p1 = fexp(v1 - m);
      float p2 = fexp(v2 - m), p3 = fexp(v3 - m);
      float ss = p0 + p1 + p2 + p3;
#pragma unroll
      for (int d = 1; d < 64; d <<= 1) ss += __shfl_xor(ss, d, 64);
      float Sinv = 1.f / ss;
      if (w == 0) {
        aw[lane] = p0 * Sinv; aw[64 + lane] = p1 * Sinv;
        aw[128 + lane] = p2 * Sinv; aw[192 + lane] = p3 * Sinv;
      }
    } else {
      if (t < 256) aw[t] = 1.f / 256.f;
    }
    __syncthreads();
    {
      // r-phase: 8 groups of 32 atoms; d = output dim (0..127)
      int d = t & 127, grp = t >> 7;
      const unsigned* xc = xl + grp * 32 * 65 + (d >> 1);
      int hi = d & 1;
      const float* ap = aw + grp * 32;
      float r0 = 0.f, r1 = 0.f, r2 = 0.f, r3 = 0.f;
#pragma unroll 4
      for (int n2 = 0; n2 < 32; n2 += 4) {
        unsigned u0 = xc[n2 * 65], u1 = xc[(n2 + 1) * 65];
        unsigned u2 = xc[(n2 + 2) * 65], u3 = xc[(n2 + 3) * 65];
        r0 += ap[n2] * (hi ? hhi(u0) : hlo(u0));
        r1 += ap[n2 + 1] * (hi ? hhi(u1) : hlo(u1));
        r2 += ap[n2 + 2] * (hi ? hhi(u2) : hlo(u2));
        r3 += ap[n2 + 3] * (hi ? hhi(u3) : hlo(u3));
      }
      gates[t] = (r0 + r1) + (r2 + r3);
    }
    __syncthreads();
    if (t < 128) {
      float rd = 0.f;
#pragma unroll
      for (int g = 0; g < 8; g++) rd += gates[g * 128 + t];
      float rp = __shfl_xor(rd, 1, 64);
      if ((t & 1) == 0) qu[64 + (t >> 1)] = packh(rd, rp);
    }
    __syncthreads();
  }
  // memory LSTM gates (split halves like s2s gates)
  {
    const uint4* mp = ((const uint4*)(mwihh + (size_t)t0 * 256)) + hi2 * 16;
    float a0 = 0.f, a1 = 0.f, a2 = 0.f, a3 = 0.f;
#pragma unroll
    for (int i = 0; i < 16; i++) {
      uint4 wv = mp[i], qv = q4[hi2 * 16 + i];
      a0 = fdot2u(wv.x, qv.x, a0);
      a1 = fdot2u(wv.y, qv.y, a1);
      a2 = fdot2u(wv.z, qv.z, a2);
      a3 = fdot2u(wv.w, qv.w, a3);
    }
    float mb = (hi2 == 0) ? (mbih[t0] + mbhh[t0]) : 0.f;
    gates[t] = mb + ((a0 + a1) + (a2 + a3));
  }
  __syncthreads();
  if (t < 128) {
    float g0 = gates[t] + gates[512 + t];
    float g2 = gates[256 + t] + gates[768 + t];
    float g3 = gates[384 + t] + gates[896 + t];
    float ig = sigf(g0);
    float gg = ftanh(g2);
    float og = sigf(g3);
    float cx = ig * gg;
    float hx = og * ftanh(cx);
    cst[t] = hx;
    out[64 + s * 128 + t] = hx;
    out[64 + 8192 + s * 128 + t] = cx;
  }
  __syncthreads();
  if (t < 128) {
    float acc = l1b[t];
    const float4* w4 = (const float4*)(l1w + (size_t)t * 128);
    const float4* h4 = (const float4*)cst;
#pragma unroll 8
    for (int k = 0; k < 32; k++) {
      float4 a = w4[k], b = h4[k];
      acc += a.x * b.x + a.y * b.y + a.z * b.z + a.w * b.w;
    }
    red[t] = fmaxf(acc, 0.f) * l3w[t];
  } else if (t < 256) {
    red[t] = 0.f;
  }
  __syncthreads();
  for (int off = 128; off; off >>= 1) {
    if (t < off) red[t] += red[t + off];
    __syncthreads();
  }
  if (t == 0) out[s] = red[0] + l3b[0];
}

// ---------------------------------------------------------------------------
extern "C" void kernel_launch(void* const* d_in, const int* in_sizes, int n_in,
                              void* d_out, int out_size, void* d_ws,
                              size_t ws_size, hipStream_t stream) {
  const float* data       = (const float*)d_in[0];
  const float* lin0_w     = (const float*)d_in[1];
  const float* lin0_b     = (const float*)d_in[2];
  const float* attn_in_w  = (const float*)d_in[3];
  const float* attn_in_b  = (const float*)d_in[4];
  const float* attn_out_w = (const float*)d_in[5];
  const float* attn_out_b = (const float*)d_in[6];
  const float* ln1_g      = (const float*)d_in[7];
  const float* ln1_b      = (const float*)d_in[8];
  const float* ff_w1      = (const float*)d_in[9];
  const float* ff_b1      = (const float*)d_in[10];
  const float* ff_w2      = (const float*)d_in[11];
  const float* ff_b2      = (const float*)d_in[12];
  const float* ln2_g      = (const float*)d_in[13];
  const float* ln2_b      = (const float*)d_in[14];
  const float* s2s_wih    = (const float*)d_in[15];
  const float* s2s_whh    = (const float*)d_in[16];
  const float* s2s_bih    = (const float*)d_in[17];
  const float* s2s_bhh    = (const float*)d_in[18];
  const float* mem_wih    = (const float*)d_in[19];
  const float* mem_bih    = (const float*)d_in[21];
  const float* mem_bhh    = (const float*)d_in[22];
  const float* lin1_w     = (const float*)d_in[23];
  const float* lin1_b     = (const float*)d_in[24];
  const float* lin3_w     = (const float*)d_in[25];
  const float* lin3_b     = (const float*)d_in[26];
  float* out = (float*)d_out;

  char* p = (char*)d_ws;
  float* x = (float*)p;                      p += (size_t)16384 * 128 * 4;
  unsigned short* xb = (unsigned short*)p;   p += (size_t)16384 * 128 * 2;
  unsigned short* wqkv = (unsigned short*)p; p += (size_t)294912 * 2;
  unsigned short* wout = (unsigned short*)p; p += (size_t)98304 * 2;
  unsigned short* w1h = (unsigned short*)p;  p += (size_t)1572864 * 2;
  unsigned short* w2h = (unsigned short*)p;  p += (size_t)1572864 * 2;
  unsigned short* wihh = (unsigned short*)p; p += (size_t)131072 * 2;
  unsigned short* whhh = (unsigned short*)p; p += (size_t)65536 * 2;
  unsigned short* mwihh = (unsigned short*)p; p += (size_t)131072 * 2;

  convw_kernel<<<15104, 256, 0, stream>>>(
      attn_in_w, attn_out_w, ff_w1, ff_w2, s2s_wih, s2s_whh, mem_wih,
      wqkv, wout, w1h, w2h, wihh, whhh, mwihh);
  lin0_kernel<<<8192, 256, 0, stream>>>(data, lin0_w, lin0_b, x, xb);

  for (int l = 0; l < 6; l++) {
    layer_kernel<<<512, 256, 0, stream>>>(
        xb, wqkv + (size_t)l * 49152, attn_in_b + l * 384,
        wout + (size_t)l * 16384, attn_out_b + l * 128,
        ln1_g + l * 128, ln1_b + l * 128,
        w1h + (size_t)l * 262144, ff_b1 + l * 2048,
        w2h + (size_t)l * 262144, ff_b2 + l * 128,
        ln2_g + l * 128, ln2_b + l * 128, x, xb);
  }

  s2s_kernel<<<64, 1024, 0, stream>>>(
      xb, wihh, whhh, s2s_bih, s2s_bhh,
      mwihh, mem_bih, mem_bhh, lin1_w, lin1_b, lin3_w, lin3_b, out);
}

// Round 12
// 411.154 us; speedup vs baseline: 1.1064x; 1.1064x over previous
//
#include <hip/hip_runtime.h>
#include <math.h>

// S=64 seq, B=256 atoms, N=16384, D=128, H=8, HD=16, DFF=2048, NL=6.
// R25 = R24 layers (unchanged) + s2s fixed: R24 doubled waves (16/CU) but
// moved gate weights to per-step L2 re-reads -> 6x reload latency on the
// critical path, s2s 49->98us (VGPR=64 proved nothing stayed resident).
// Now: PERSISTENT HALF-ROW weights at 1024 threads -- each thread of the
// (t, t+512) pair holds wih half-row (16 uint4 = 64 VGPR) + whh half-row
// (8 uint4 = 32 VGPR) = 96 persistent VGPR, fits the 128 cap at 4
// waves/SIMD. Chain halved vs R23 AND waves doubled.

typedef _Float16 __attribute__((ext_vector_type(8))) f16x8;
typedef __attribute__((ext_vector_type(4))) float f32x4;
typedef _Float16 __attribute__((ext_vector_type(2))) h16x2;

__device__ __forceinline__ unsigned short f2h(float f) {
  union { _Float16 h; unsigned short s; } x; x.h = (_Float16)f; return x.s;
}
__device__ __forceinline__ float h2f(unsigned short u) {
  union { unsigned short s; _Float16 h; } x; x.s = u; return (float)x.h;
}
__device__ __forceinline__ unsigned packh(float a, float b) {
  return (unsigned)f2h(a) | ((unsigned)f2h(b) << 16);
}
__device__ __forceinline__ uint2 pk4(float a, float b, float c, float d) {
  return make_uint2(packh(a, b), packh(c, d));
}
__device__ __forceinline__ float hlo(unsigned u) {
  union { unsigned short s; _Float16 h; } x; x.s = (unsigned short)(u & 0xffff);
  return (float)x.h;
}
__device__ __forceinline__ float hhi(unsigned u) {
  union { unsigned short s; _Float16 h; } x; x.s = (unsigned short)(u >> 16);
  return (float)x.h;
}
__device__ __forceinline__ float fdot2u(unsigned a, unsigned b, float c) {
#if __has_builtin(__builtin_amdgcn_fdot2)
  union U { unsigned u; h16x2 h; };
  U x, y; x.u = a; y.u = b;
  return __builtin_amdgcn_fdot2(x.h, y.h, c, false);
#else
  return c + hlo(a) * hlo(b) + hhi(a) * hhi(b);
#endif
}
// fast hardware transcendentals (v_exp_f32)
__device__ __forceinline__ float fexp(float x) { return __expf(x); }
__device__ __forceinline__ float sigf(float x) {
  return 1.f / (1.f + __expf(-x));
}
__device__ __forceinline__ float ftanh(float x) {
  float e = __expf(2.f * x);
  return 1.f - 2.f / (e + 1.f);
}

// async 16B global->LDS; LDS base wave-uniform (+ lane*16 implicit).
__device__ __forceinline__ void gl2lds16(const void* g, void* l) {
  __builtin_amdgcn_global_load_lds(
      (const __attribute__((address_space(1))) unsigned int*)g,
      (__attribute__((address_space(3))) unsigned int*)l, 16, 0, 0);
}

// ---------------------------------------------------------------------------
// weight conversion: everything -> f16, frag-major (see R14 comment).
// ---------------------------------------------------------------------------
__global__ __launch_bounds__(256) void convw_kernel(
    const float* __restrict__ aiw, const float* __restrict__ aow,
    const float* __restrict__ w1, const float* __restrict__ w2,
    const float* __restrict__ wih, const float* __restrict__ whh,
    const float* __restrict__ mwih,
    unsigned short* __restrict__ o0, unsigned short* __restrict__ o1,
    unsigned short* __restrict__ o2, unsigned short* __restrict__ o3,
    unsigned short* __restrict__ o4, unsigned short* __restrict__ o5,
    unsigned short* __restrict__ o6) {
  int i = blockIdx.x * 256 + threadIdx.x;
  if (i < 294912) {
    int l = i / 49152, o = i % 49152;
    int j = o & 7, fr = (o >> 3) & 15, fq = (o >> 7) & 3, ks = (o >> 9) & 3,
        rb = o >> 11;
    o0[i] = f2h(aiw[l * 49152 + (rb * 16 + fr) * 128 + ks * 32 + fq * 8 + j]);
  } else if (i < 393216) {
    int ii = i - 294912;
    int l = ii / 16384, o = ii % 16384;
    int j = o & 7, fr = (o >> 3) & 15, fq = (o >> 7) & 3, ks = (o >> 9) & 3,
        rb = o >> 11;
    o1[ii] = f2h(aow[l * 16384 + (rb * 16 + fr) * 128 + ks * 32 + fq * 8 + j]);
  } else if (i < 1966080) {
    int ii = i - 393216;
    int l = ii >> 18, o = ii & 262143;
    int j = o & 7, fr = (o >> 3) & 15, fq = (o >> 7) & 3, ks = (o >> 9) & 3,
        rb = o >> 11;
    o2[ii] = f2h(w1[l * 262144 + (rb * 16 + fr) * 128 + ks * 32 + fq * 8 + j]);
  } else if (i < 3538944) {
    int ii = i - 1966080;
    int l = ii >> 18, o = ii & 262143;
    int j = o & 7, fr = (o >> 3) & 15, fq = (o >> 7) & 3, ks = (o >> 9) & 63,
        rb = o >> 15;
    o3[ii] = f2h(w2[l * 262144 + (rb * 16 + fr) * 2048 + ks * 32 + fq * 8 + j]);
  } else if (i < 3670016) {
    int j = i - 3538944; o4[j] = f2h(wih[j]);
  } else if (i < 3735552) {
    int j = i - 3670016; o5[j] = f2h(whh[j]);
  } else {
    int j = i - 3735552; o6[j] = f2h(mwih[j]);
  }
}

// ---------------------------------------------------------------------------
// lin0: x = relu(data @ w^T + b), writes fp32 x and f16 xb
// ---------------------------------------------------------------------------
__global__ __launch_bounds__(256) void lin0_kernel(
    const float* __restrict__ data, const float* __restrict__ w,
    const float* __restrict__ b, float* __restrict__ x,
    unsigned short* __restrict__ xb) {
  int i = blockIdx.x * 256 + threadIdx.x;
  int n = i >> 7, d = i & 127;
  float v = b[d] + data[n * 3 + 0] * w[d * 3 + 0]
                 + data[n * 3 + 1] * w[d * 3 + 1]
                 + data[n * 3 + 2] * w[d * 3 + 2];
  v = fmaxf(v, 0.0f);
  x[i] = v;
  xb[i] = f2h(v);
}

// ---------------------------------------------------------------------------
// Fused transformer LAYER: block = (atom b, s-half), 256 threads, 4 waves.
// ---------------------------------------------------------------------------
__global__ __launch_bounds__(256, 2) void layer_kernel(
    const unsigned short* __restrict__ xbg,
    const unsigned short* __restrict__ wqkv, const float* __restrict__ bqkv,
    const unsigned short* __restrict__ wout, const float* __restrict__ bout,
    const float* __restrict__ ln1g, const float* __restrict__ ln1b,
    const unsigned short* __restrict__ w1, const float* __restrict__ b1,
    const unsigned short* __restrict__ w2, const float* __restrict__ b2,
    const float* __restrict__ ln2g, const float* __restrict__ ln2b,
    float* __restrict__ xio, unsigned short* __restrict__ xbo) {
  // shorts: Xs[0,8192) Ks[8192,16384) VT[16384,24576) Qs[24576,28672)
  __shared__ __align__(16) unsigned short SM[28672];
  __shared__ float psum[4][32], psq[4][32];
  __shared__ float2 stats[32];
  __shared__ __align__(16) uint4 zchunk;

  unsigned short* Xs = SM;             // x input -> P slots -> Hs buf0
  unsigned short* Ks = SM + 8192;      // K [s][feat] -> Hs buf1
  unsigned short* VT = SM + 16384;     // V^T [feat][s] -> AOs
  unsigned short* AOs = SM + 16384;    // AO [s][feat] 32x128
  unsigned short* Qs = SM + 24576;     // own-half Q [s][feat] 32x128 -> Xn
  unsigned short* Xn = SM + 24576;

  int tid = threadIdx.x, w = tid >> 6, lane = tid & 63;
  int b = blockIdx.x >> 1, half = blockIdx.x & 1;
  int r4 = lane >> 4, cs = lane & 15;
  int fr = lane & 15, fq = lane >> 4;

  if (tid == 0) zchunk = make_uint4(0u, 0u, 0u, 0u);

  // ---- phase 0: stage full x tile (rows 0..63) ----
#pragma unroll
  for (int i = 0; i < 4; i++) {
    int issue = w * 4 + i;
    int row = issue * 4 + r4;
    int g = cs ^ (row & 7);
    gl2lds16(xbg + (size_t)(row * 256 + b) * 128 + g * 8,
             (char*)Xs + issue * 1024);
  }
  // preload pass-Q weights (8 frags = 32 VGPR) while staging is in flight
  f16x8 wq[4][2];
#pragma unroll
  for (int ks = 0; ks < 4; ks++)
#pragma unroll
    for (int ni = 0; ni < 2; ni++)
      wq[ks][ni] = *(const f16x8*)(wqkv + (size_t)(w * 2 + ni) * 2048 +
                                   ks * 512 + fq * 128 + fr * 8);
  __syncthreads();

  // ---- phase 1: QKV, 3 passes, ONE barrier ----
  // Pass Q (SWAPPED: A=W, B=x): own 32 rows. D[qfeat][s] -> store Qs[s][qfeat]
  {
    f32x4 acc[2][2];
#pragma unroll
    for (int i = 0; i < 2; i++)
#pragma unroll
      for (int j = 0; j < 2; j++) acc[i][j] = (f32x4){0.f, 0.f, 0.f, 0.f};
#pragma unroll
    for (int ks = 0; ks < 4; ks++) {
      f16x8 bx[2];
#pragma unroll
      for (int mi2 = 0; mi2 < 2; mi2++) {
        int row = half * 32 + mi2 * 16 + fr;
        int kq = (ks * 4 + fq) ^ (row & 7);
        bx[mi2] = *(const f16x8*)(Xs + row * 128 + kq * 8);
      }
#pragma unroll
      for (int mi2 = 0; mi2 < 2; mi2++)
#pragma unroll
        for (int ni = 0; ni < 2; ni++)
          acc[mi2][ni] = __builtin_amdgcn_mfma_f32_16x16x32_f16(
              wq[ks][ni], bx[mi2], acc[mi2][ni], 0, 0, 0);
    }
#pragma unroll
    for (int ni = 0; ni < 2; ni++) {
      int fb = (w * 2 + ni) * 16 + fq * 4;
      float4 bv = *(const float4*)&bqkv[fb];
#pragma unroll
      for (int mi2 = 0; mi2 < 2; mi2++) {
        int srow = mi2 * 16 + fr;  // local 0..31
        *(uint2*)(Qs + srow * 128 + (((fb >> 3) ^ (srow & 7)) << 3) +
                  (fb & 7)) =
            pk4(acc[mi2][ni][0] + bv.x, acc[mi2][ni][1] + bv.y,
                acc[mi2][ni][2] + bv.z, acc[mi2][ni][3] + bv.w);
      }
    }
  }
  // Pass K (SWAPPED): full 64 rows. D[kfeat][s] -> store Ks[s][kfeat]
  {
    // preload all 8 K-weight frags
    f16x8 wk[4][2];
#pragma unroll
    for (int ks = 0; ks < 4; ks++)
#pragma unroll
      for (int ni = 0; ni < 2; ni++)
        wk[ks][ni] = *(const f16x8*)(wqkv + (size_t)(8 + w * 2 + ni) * 2048 +
                                     ks * 512 + fq * 128 + fr * 8);
    f32x4 acc[4][2];
#pragma unroll
    for (int i = 0; i < 4; i++)
#pragma unroll
      for (int j = 0; j < 2; j++) acc[i][j] = (f32x4){0.f, 0.f, 0.f, 0.f};
#pragma unroll
    for (int ks = 0; ks < 4; ks++) {
      f16x8 bx[4];
#pragma unroll
      for (int mi = 0; mi < 4; mi++) {
        int row = mi * 16 + fr;
        int kq = (ks * 4 + fq) ^ (row & 7);
        bx[mi] = *(const f16x8*)(Xs + row * 128 + kq * 8);
      }
#pragma unroll
      for (int mi = 0; mi < 4; mi++)
#pragma unroll
        for (int ni = 0; ni < 2; ni++)
          acc[mi][ni] = __builtin_amdgcn_mfma_f32_16x16x32_f16(
              wk[ks][ni], bx[mi], acc[mi][ni], 0, 0, 0);
    }
#pragma unroll
    for (int ni = 0; ni < 2; ni++) {
      int fb = (w * 2 + ni) * 16 + fq * 4;
      float4 bv = *(const float4*)&bqkv[128 + fb];
#pragma unroll
      for (int mi = 0; mi < 4; mi++) {
        int srow = mi * 16 + fr;
        *(uint2*)(Ks + srow * 128 + (((fb >> 3) ^ (srow & 7)) << 3) +
                  (fb & 7)) =
            pk4(acc[mi][ni][0] + bv.x, acc[mi][ni][1] + bv.y,
                acc[mi][ni][2] + bv.z, acc[mi][ni][3] + bv.w);
      }
    }
  }
  // Pass V (UNSWAPPED: A=x, B=W): D[s][vfeat] -> store VT[vfeat][s] packed
  {
    // preload all 8 V-weight frags
    f16x8 wv[4][2];
#pragma unroll
    for (int ks = 0; ks < 4; ks++)
#pragma unroll
      for (int ni = 0; ni < 2; ni++)
        wv[ks][ni] = *(const f16x8*)(wqkv + (size_t)(16 + w * 2 + ni) * 2048 +
                                     ks * 512 + fq * 128 + fr * 8);
    f32x4 acc[4][2];
#pragma unroll
    for (int i = 0; i < 4; i++)
#pragma unroll
      for (int j = 0; j < 2; j++) acc[i][j] = (f32x4){0.f, 0.f, 0.f, 0.f};
#pragma unroll
    for (int ks = 0; ks < 4; ks++) {
      f16x8 ax[4];
#pragma unroll
      for (int mi = 0; mi < 4; mi++) {
        int row = mi * 16 + fr;
        int kq = (ks * 4 + fq) ^ (row & 7);
        ax[mi] = *(const f16x8*)(Xs + row * 128 + kq * 8);
      }
#pragma unroll
      for (int mi = 0; mi < 4; mi++)
#pragma unroll
        for (int ni = 0; ni < 2; ni++)
          acc[mi][ni] = __builtin_amdgcn_mfma_f32_16x16x32_f16(
              ax[mi], wv[ks][ni], acc[mi][ni], 0, 0, 0);
    }
#pragma unroll
    for (int ni = 0; ni < 2; ni++) {
      int feat = (w * 2 + ni) * 16 + fr;
      float bv = bqkv[256 + feat];
#pragma unroll
      for (int mi = 0; mi < 4; mi++) {
        int sb = mi * 16 + fq * 4;
        *(uint2*)(VT + feat * 64 + (((sb >> 3) ^ (feat & 7)) << 3) +
                  (sb & 7)) =
            pk4(acc[mi][ni][0] + bv, acc[mi][ni][1] + bv,
                acc[mi][ni][2] + bv, acc[mi][ni][3] + bv);
      }
    }
  }
  // preload Wout frags (8 = 32 VGPR) -- consumed in phase 4, issued here so
  // L2 latency hides under the attention phase.
  f16x8 wo[4][2];
#pragma unroll
  for (int ks = 0; ks < 4; ks++)
#pragma unroll
    for (int ni = 0; ni < 2; ni++)
      wo[ks][ni] = *(const f16x8*)(wout + (size_t)(w * 2 + ni) * 2048 +
                                   ks * 512 + fq * 128 + fr * 8);
  __syncthreads();  // QKV published; Xs reads done -> Xs reusable as P slots

  // ---- attention: wave w -> heads {2w, 2w+1}, own 32 rows; P in Xs ----
  f32x4 po[2][2];
#pragma unroll
  for (int i = 0; i < 2; i++)
#pragma unroll
    for (int j = 0; j < 2; j++) po[i][j] = (f32x4){0.f, 0.f, 0.f, 0.f};
  {
    unsigned short* Pb = Xs + w * 2048;  // 4KB wave-private slot
#pragma unroll
    for (int hi = 0; hi < 2; hi++) {
      int h = w * 2 + hi;
      f16x8 afH[2], bfH[4];
#pragma unroll
      for (int mi2 = 0; mi2 < 2; mi2++) {
        int qrow = mi2 * 16 + fr;  // local 0..31
        const unsigned short* pa =
            (fq < 2) ? (Qs + qrow * 128 + (((h * 2 + fq) ^ (qrow & 7)) << 3))
                     : (const unsigned short*)&zchunk;
        afH[mi2] = *(const f16x8*)pa;
      }
#pragma unroll
      for (int ti = 0; ti < 4; ti++) {
        int trow = ti * 16 + fr;
        const unsigned short* pb =
            (fq < 2) ? (Ks + trow * 128 + (((h * 2 + fq) ^ (trow & 7)) << 3))
                     : (const unsigned short*)&zchunk;
        bfH[ti] = *(const f16x8*)pb;
      }
      f32x4 sc[2][4];
#pragma unroll
      for (int i = 0; i < 2; i++)
#pragma unroll
        for (int j = 0; j < 4; j++) sc[i][j] = (f32x4){0.f, 0.f, 0.f, 0.f};
#pragma unroll
      for (int mi2 = 0; mi2 < 2; mi2++)
#pragma unroll
        for (int ti = 0; ti < 4; ti++)
          sc[mi2][ti] = __builtin_amdgcn_mfma_f32_16x16x32_f16(
              afH[mi2], bfH[ti], sc[mi2][ti], 0, 0, 0);
#pragma unroll
      for (int mi2 = 0; mi2 < 2; mi2++) {
#pragma unroll
        for (int r = 0; r < 4; r++) {
          float m = -1e30f;
#pragma unroll
          for (int ti = 0; ti < 4; ti++) m = fmaxf(m, sc[mi2][ti][r]);
          m = fmaxf(m, __shfl_xor(m, 1, 64));
          m = fmaxf(m, __shfl_xor(m, 2, 64));
          m = fmaxf(m, __shfl_xor(m, 4, 64));
          m = fmaxf(m, __shfl_xor(m, 8, 64));
          m *= 0.25f;
          float ss = 0.f;
#pragma unroll
          for (int ti = 0; ti < 4; ti++) {
            float p = fexp(sc[mi2][ti][r] * 0.25f - m);
            sc[mi2][ti][r] = p;
            ss += p;
          }
          ss += __shfl_xor(ss, 1, 64);
          ss += __shfl_xor(ss, 2, 64);
          ss += __shfl_xor(ss, 4, 64);
          ss += __shfl_xor(ss, 8, 64);
          float inv = 1.f / ss;
          int prow = mi2 * 16 + fq * 4 + r;  // local 0..31
#pragma unroll
          for (int ti = 0; ti < 4; ti++) {
            int t = ti * 16 + fr;
            Pb[prow * 64 + (((t >> 3) ^ (prow & 7)) << 3) + (t & 7)] =
                f2h(sc[mi2][ti][r] * inv);
          }
        }
      }
      // PV SWAPPED: A=VT frag, B=P frag -> D[vfeat][s]
#pragma unroll
      for (int ks2 = 0; ks2 < 2; ks2++) {
        f16x8 bp[2], avt;
#pragma unroll
        for (int si2 = 0; si2 < 2; si2++) {
          int prow = si2 * 16 + fr;
          int kq = (ks2 * 4 + fq) ^ (prow & 7);
          bp[si2] = *(const f16x8*)(Pb + prow * 64 + kq * 8);
        }
        {
          int vrow = h * 16 + fr;
          int kq = (ks2 * 4 + fq) ^ (vrow & 7);
          avt = *(const f16x8*)(VT + vrow * 64 + kq * 8);
        }
#pragma unroll
        for (int si2 = 0; si2 < 2; si2++)
          po[hi][si2] = __builtin_amdgcn_mfma_f32_16x16x32_f16(
              avt, bp[si2], po[hi][si2], 0, 0, 0);
      }
    }
  }
  __syncthreads();  // all PV reads of VT done -> VT reusable as AOs
  // AO store: lane holds 4 consecutive vfeat at fixed s -> b64
#pragma unroll
  for (int hi = 0; hi < 2; hi++) {
    int fb = (w * 2 + hi) * 16 + fq * 4;
#pragma unroll
    for (int si2 = 0; si2 < 2; si2++) {
      int srow = si2 * 16 + fr;
      *(uint2*)(AOs + srow * 128 + (((fb >> 3) ^ (srow & 7)) << 3) +
                (fb & 7)) =
          pk4(po[hi][si2][0], po[hi][si2][1], po[hi][si2][2], po[hi][si2][3]);
    }
  }
  __syncthreads();  // AO published

  // ---- phase 4 (SWAPPED): v = x + ao @ Wout^T + bias ; LN1 -> Xn ----
  {
    f32x4 acc[2][2];
#pragma unroll
    for (int i = 0; i < 2; i++)
#pragma unroll
      for (int j = 0; j < 2; j++) acc[i][j] = (f32x4){0.f, 0.f, 0.f, 0.f};
#pragma unroll
    for (int ks = 0; ks < 4; ks++) {
      f16x8 bao[2];
#pragma unroll
      for (int mi2 = 0; mi2 < 2; mi2++) {
        int row = mi2 * 16 + fr;
        int kq = (ks * 4 + fq) ^ (row & 7);
        bao[mi2] = *(const f16x8*)(AOs + row * 128 + kq * 8);
      }
#pragma unroll
      for (int mi2 = 0; mi2 < 2; mi2++)
#pragma unroll
        for (int ni = 0; ni < 2; ni++)
          acc[mi2][ni] = __builtin_amdgcn_mfma_f32_16x16x32_f16(
              wo[ks][ni], bao[mi2], acc[mi2][ni], 0, 0, 0);
    }
    // lane: s = mi2*16+fr (local), feats = (w*2+ni)*16 + fq*4 + r
    float v4[2][2][4];  // [ni][mi2][r]
    float psA[2] = {0.f, 0.f}, psQ[2] = {0.f, 0.f};
#pragma unroll
    for (int ni = 0; ni < 2; ni++) {
      int fb = (w * 2 + ni) * 16 + fq * 4;
      float4 bv = *(const float4*)&bout[fb];
#pragma unroll
      for (int mi2 = 0; mi2 < 2; mi2++) {
        int rowg = half * 32 + mi2 * 16 + fr;
        float4 rs = *(const float4*)&xio[(size_t)(rowg * 256 + b) * 128 + fb];
        float t0 = acc[mi2][ni][0] + bv.x + rs.x;
        float t1 = acc[mi2][ni][1] + bv.y + rs.y;
        float t2 = acc[mi2][ni][2] + bv.z + rs.z;
        float t3 = acc[mi2][ni][3] + bv.w + rs.w;
        v4[ni][mi2][0] = t0; v4[ni][mi2][1] = t1;
        v4[ni][mi2][2] = t2; v4[ni][mi2][3] = t3;
        psA[mi2] += (t0 + t1) + (t2 + t3);
        psQ[mi2] += (t0 * t0 + t1 * t1) + (t2 * t2 + t3 * t3);
      }
    }
#pragma unroll
    for (int mi2 = 0; mi2 < 2; mi2++) {
      psA[mi2] += __shfl_xor(psA[mi2], 16, 64);
      psA[mi2] += __shfl_xor(psA[mi2], 32, 64);
      psQ[mi2] += __shfl_xor(psQ[mi2], 16, 64);
      psQ[mi2] += __shfl_xor(psQ[mi2], 32, 64);
    }
    if (fq == 0) {
#pragma unroll
      for (int mi2 = 0; mi2 < 2; mi2++) {
        psum[w][mi2 * 16 + fr] = psA[mi2];
        psq[w][mi2 * 16 + fr] = psQ[mi2];
      }
    }
    __syncthreads();  // A
    if (tid < 32) {
      float S = 0.f, Q = 0.f;
#pragma unroll
      for (int ww = 0; ww < 4; ww++) { S += psum[ww][tid]; Q += psq[ww][tid]; }
      float m = S * (1.f / 128.f);
      float var = Q * (1.f / 128.f) - m * m;
      stats[tid] = make_float2(m, rsqrtf(var + 1e-5f));
    }
    __syncthreads();  // B
#pragma unroll
    for (int ni = 0; ni < 2; ni++) {
      int fb = (w * 2 + ni) * 16 + fq * 4;
      float4 g4 = *(const float4*)&ln1g[fb];
      float4 b4 = *(const float4*)&ln1b[fb];
#pragma unroll
      for (int mi2 = 0; mi2 < 2; mi2++) {
        int srow = mi2 * 16 + fr;
        float2 st = stats[srow];
        float y0 = (v4[ni][mi2][0] - st.x) * st.y * g4.x + b4.x;
        float y1 = (v4[ni][mi2][1] - st.x) * st.y * g4.y + b4.y;
        float y2 = (v4[ni][mi2][2] - st.x) * st.y * g4.z + b4.z;
        float y3 = (v4[ni][mi2][3] - st.x) * st.y * g4.w + b4.w;
        *(uint2*)(Xn + srow * 128 + (((fb >> 3) ^ (srow & 7)) << 3) +
                  (fb & 7)) = pk4(y0, y1, y2, y3);
      }
    }
  }
  __syncthreads();  // C: LN1 out published; Xs+Ks dead -> Hs dbuf (2x16KB)

  // hoisted FFN x fragments (B-operand; local 32 rows)
  f16x8 xfragF[4][2];
#pragma unroll
  for (int ks = 0; ks < 4; ks++)
#pragma unroll
    for (int mi2 = 0; mi2 < 2; mi2++) {
      int rowl = mi2 * 16 + fr;
      int kq = (ks * 4 + fq) ^ (rowl & 7);
      xfragF[ks][mi2] = *(const f16x8*)(Xn + rowl * 128 + kq * 8);
    }

  // ---- FFN (SWAPPED): 8 chunks x 256 hidden. H stored [s][hcol] packed.
  f32x4 acc2[2][2];
#pragma unroll
  for (int i = 0; i < 2; i++)
#pragma unroll
    for (int j = 0; j < 2; j++) acc2[i][j] = (f32x4){0.f, 0.f, 0.f, 0.f};

  for (int c = 0; c < 8; c++) {
    unsigned short* Hcur = SM + (c & 1) * 8192;
    // preload full ff1 weight set for this chunk (16 frags = 64 VGPR)
    f16x8 aw1[4][4];
#pragma unroll
    for (int ks = 0; ks < 4; ks++)
#pragma unroll
      for (int ni = 0; ni < 4; ni++)
        aw1[ks][ni] = *(const f16x8*)(w1 + (size_t)(c * 16 + w * 4 + ni) *
                                              2048 +
                                      ks * 512 + fq * 128 + fr * 8);
    f32x4 acc1[2][4];
#pragma unroll
    for (int i = 0; i < 2; i++)
#pragma unroll
      for (int j = 0; j < 4; j++) acc1[i][j] = (f32x4){0.f, 0.f, 0.f, 0.f};
#pragma unroll
    for (int ks = 0; ks < 4; ks++)
#pragma unroll
      for (int mi2 = 0; mi2 < 2; mi2++)
#pragma unroll
        for (int ni = 0; ni < 4; ni++)
          acc1[mi2][ni] = __builtin_amdgcn_mfma_f32_16x16x32_f16(
              aw1[ks][ni], xfragF[ks][mi2], acc1[mi2][ni], 0, 0, 0);
#pragma unroll
    for (int ni = 0; ni < 4; ni++) {
      int hb = (w * 4 + ni) * 16 + fq * 4;  // 0..255
      float4 bv = *(const float4*)&b1[c * 256 + hb];
#pragma unroll
      for (int mi2 = 0; mi2 < 2; mi2++) {
        int srow = mi2 * 16 + fr;
        *(uint2*)(Hcur + srow * 256 + (((hb >> 3) ^ (srow & 7)) << 3) +
                  (hb & 7)) =
            pk4(fmaxf(acc1[mi2][ni][0] + bv.x, 0.f),
                fmaxf(acc1[mi2][ni][1] + bv.y, 0.f),
                fmaxf(acc1[mi2][ni][2] + bv.z, 0.f),
                fmaxf(acc1[mi2][ni][3] + bv.w, 0.f));
      }
    }
    // preload full ff2 weight set BEFORE the barrier (16 frags = 64 VGPR);
    // their ~200cy L2 latency hides under the barrier wait.
    f16x8 aw2[8][2];
#pragma unroll
    for (int ks2 = 0; ks2 < 8; ks2++)
#pragma unroll
      for (int ni = 0; ni < 2; ni++)
        aw2[ks2][ni] = *(const f16x8*)(w2 + (size_t)(w * 2 + ni) * 32768 +
                                       (c * 8 + ks2) * 512 + fq * 128 +
                                       fr * 8);
    __syncthreads();  // Hcur visible; dbuf -> 1 barrier/chunk
#pragma unroll
    for (int ks2 = 0; ks2 < 8; ks2++) {
      f16x8 bh[2];
#pragma unroll
      for (int mi2 = 0; mi2 < 2; mi2++) {
        int row = mi2 * 16 + fr;
        int kq = (ks2 * 4 + fq) ^ (row & 7);
        bh[mi2] = *(const f16x8*)(Hcur + row * 256 + kq * 8);
      }
#pragma unroll
      for (int mi2 = 0; mi2 < 2; mi2++)
#pragma unroll
        for (int ni = 0; ni < 2; ni++)
          acc2[mi2][ni] = __builtin_amdgcn_mfma_f32_16x16x32_f16(
              aw2[ks2][ni], bh[mi2], acc2[mi2][ni], 0, 0, 0);
    }
  }

  // ---- FFN epilogue: +b2 + residual (Xn), LN2, write global ----
  {
    float v4[2][2][4];  // [ni][mi2][r]
    float psA[2] = {0.f, 0.f}, psQ[2] = {0.f, 0.f};
#pragma unroll
    for (int ni = 0; ni < 2; ni++) {
      int fb = (w * 2 + ni) * 16 + fq * 4;
      float4 bv = *(const float4*)&b2[fb];
#pragma unroll
      for (int mi2 = 0; mi2 < 2; mi2++) {
        int srow = mi2 * 16 + fr;
        uint2 rz = *(const uint2*)(Xn + srow * 128 +
                                   (((fb >> 3) ^ (srow & 7)) << 3) + (fb & 7));
        float t0 = acc2[mi2][ni][0] + bv.x + hlo(rz.x);
        float t1 = acc2[mi2][ni][1] + bv.y + hhi(rz.x);
        float t2 = acc2[mi2][ni][2] + bv.z + hlo(rz.y);
        float t3 = acc2[mi2][ni][3] + bv.w + hhi(rz.y);
        v4[ni][mi2][0] = t0; v4[ni][mi2][1] = t1;
        v4[ni][mi2][2] = t2; v4[ni][mi2][3] = t3;
        psA[mi2] += (t0 + t1) + (t2 + t3);
        psQ[mi2] += (t0 * t0 + t1 * t1) + (t2 * t2 + t3 * t3);
      }
    }
#pragma unroll
    for (int mi2 = 0; mi2 < 2; mi2++) {
      psA[mi2] += __shfl_xor(psA[mi2], 16, 64);
      psA[mi2] += __shfl_xor(psA[mi2], 32, 64);
      psQ[mi2] += __shfl_xor(psQ[mi2], 16, 64);
      psQ[mi2] += __shfl_xor(psQ[mi2], 32, 64);
    }
    if (fq == 0) {
#pragma unroll
      for (int mi2 = 0; mi2 < 2; mi2++) {
        psum[w][mi2 * 16 + fr] = psA[mi2];
        psq[w][mi2 * 16 + fr] = psQ[mi2];
      }
    }
    __syncthreads();
    if (tid < 32) {
      float S = 0.f, Q = 0.f;
#pragma unroll
      for (int ww = 0; ww < 4; ww++) { S += psum[ww][tid]; Q += psq[ww][tid]; }
      float m = S * (1.f / 128.f);
      float var = Q * (1.f / 128.f) - m * m;
      stats[tid] = make_float2(m, rsqrtf(var + 1e-5f));
    }
    __syncthreads();
#pragma unroll
    for (int ni = 0; ni < 2; ni++) {
      int fb = (w * 2 + ni) * 16 + fq * 4;
      float4 g4 = *(const float4*)&ln2g[fb];
      float4 b4 = *(const float4*)&ln2b[fb];
#pragma unroll
      for (int mi2 = 0; mi2 < 2; mi2++) {
        int srow = mi2 * 16 + fr;
        float2 st = stats[srow];
        float y0 = (v4[ni][mi2][0] - st.x) * st.y * g4.x + b4.x;
        float y1 = (v4[ni][mi2][1] - st.x) * st.y * g4.y + b4.y;
        float y2 = (v4[ni][mi2][2] - st.x) * st.y * g4.z + b4.z;
        float y3 = (v4[ni][mi2][3] - st.x) * st.y * g4.w + b4.w;
        size_t o = (size_t)((half * 32 + srow) * 256 + b) * 128 + fb;
        *(float4*)&xio[o] = make_float4(y0, y1, y2, y3);
        *(uint2*)&xbo[o] = pk4(y0, y1, y2, y3);
      }
    }
  }
}

// ---------------------------------------------------------------------------
// Set2Set (6 steps) + memory LSTM + lin1 + lin3. One 1024-thread block per
// segment (16 waves = 4/SIMD). Gate matvec split across (t, t+512) with
// PERSISTENT half-row weights (96 VGPR). e-phase 4 thr/atom; r-phase
// 8 groups x 32 atoms.
// ---------------------------------------------------------------------------
__global__ __launch_bounds__(1024, 1) void s2s_kernel(
    const unsigned short* __restrict__ xb,
    const unsigned short* __restrict__ wihh,
    const unsigned short* __restrict__ whhh,
    const float* __restrict__ bih, const float* __restrict__ bhh,
    const unsigned short* __restrict__ mwihh,
    const float* __restrict__ mbih, const float* __restrict__ mbhh,
    const float* __restrict__ l1w, const float* __restrict__ l1b,
    const float* __restrict__ l3w, const float* __restrict__ l3b,
    float* __restrict__ out) {
  __shared__ __align__(16) unsigned xl[256 * 65];
  __shared__ __align__(16) unsigned qu[128];
  __shared__ __align__(16) float cst[128];
  __shared__ __align__(16) float gates[1024];
  __shared__ __align__(16) float red[256];
  __shared__ __align__(16) float aw[256];
  int s = blockIdx.x, t = threadIdx.x, lane = t & 63, w = t >> 6;
  int t0 = t & 511, hi2 = t >> 9;

  // PERSISTENT half-row weights: wih 16 uint4 + whh 8 uint4 = 96 VGPR
  uint4 wreg[16], ureg[8];
  {
    const uint4* wp = ((const uint4*)(wihh + (size_t)t0 * 256)) + hi2 * 16;
#pragma unroll
    for (int i = 0; i < 16; i++) wreg[i] = wp[i];
    const uint4* up = ((const uint4*)(whhh + (size_t)t0 * 128)) + hi2 * 8;
#pragma unroll
    for (int i = 0; i < 8; i++) ureg[i] = up[i];
  }

  // stage x: 256 atoms x 128 dims f16 = 4096 uint4
  const uint4* xs4 = (const uint4*)(xb + (size_t)s * 32768);
#pragma unroll
  for (int it = 0; it < 4; it++) {
    int f = it * 1024 + t;
    uint4 v = xs4[f];
    int n = f >> 4, jc = (f & 15) * 4;
    unsigned* dst = xl + n * 65 + jc;
    dst[0] = v.x; dst[1] = v.y; dst[2] = v.z; dst[3] = v.w;
  }
  if (t < 128) cst[t] = 0.f;
  __syncthreads();

  const uint4* q4 = (const uint4*)qu;
  float bsum = (hi2 == 0) ? (bih[t0] + bhh[t0]) : 0.f;

  for (int step = 0; step < 6; step++) {
    if (step > 0) {
      float a0 = 0.f, a1 = 0.f, a2 = 0.f, a3 = 0.f;
#pragma unroll
      for (int i = 0; i < 16; i++) {
        uint4 wv = wreg[i], qv = q4[hi2 * 16 + i];
        a0 = fdot2u(wv.x, qv.x, a0);
        a1 = fdot2u(wv.y, qv.y, a1);
        a2 = fdot2u(wv.z, qv.z, a2);
        a3 = fdot2u(wv.w, qv.w, a3);
      }
#pragma unroll
      for (int i = 0; i < 8; i++) {
        uint4 uv = ureg[i], qv = q4[hi2 * 8 + i];
        a0 = fdot2u(uv.x, qv.x, a0);
        a1 = fdot2u(uv.y, qv.y, a1);
        a2 = fdot2u(uv.z, qv.z, a2);
        a3 = fdot2u(uv.w, qv.w, a3);
      }
      gates[t] = bsum + ((a0 + a1) + (a2 + a3));
    } else {
      gates[t] = bsum;
    }
    __syncthreads();
    if (t < 128) {
      float g0 = gates[t] + gates[512 + t];
      float g1 = gates[128 + t] + gates[640 + t];
      float g2 = gates[256 + t] + gates[768 + t];
      float g3 = gates[384 + t] + gates[896 + t];
      float ig = sigf(g0), fg = sigf(g1);
      float gg = ftanh(g2), og = sigf(g3);
      float cn = fg * cst[t] + ig * gg;
      cst[t] = cn;
      float hn = og * ftanh(cn);
      float hp = __shfl_xor(hn, 1, 64);
      if ((t & 1) == 0) qu[t >> 1] = packh(hn, hp);
    }
    __syncthreads();
    if (step > 0) {
      // e-phase: 4 threads per atom, 16-dim (8 uint) segments
      int n = t >> 2, sub = t & 3;
      const unsigned* xr = xl + n * 65 + sub * 16;
      float e0 = 0.f, e1 = 0.f;
#pragma unroll
      for (int i = 0; i < 16; i += 2) {
        e0 = fdot2u(xr[i], qu[sub * 16 + i], e0);
        e1 = fdot2u(xr[i + 1], qu[sub * 16 + i + 1], e1);
      }
      float e = e0 + e1;
      e += __shfl_xor(e, 1, 64);
      e += __shfl_xor(e, 2, 64);
      if (sub == 0) red[n] = e;
      __syncthreads();
      float v0 = red[lane], v1 = red[64 + lane];
      float v2 = red[128 + lane], v3 = red[192 + lane];
      float m = fmaxf(fmaxf(v0, v1), fmaxf(v2, v3));
#pragma unroll
      for (int d = 1; d < 64; d <<= 1) m = fmaxf(m, __shfl_xor(m, d, 64));
      float p0 = fexp(v0 - m), p1 = fexp(v1 - m);
      float p2 = fexp(v2 - m), p3 = fexp(v3 - m);
      float ss = p0 + p1 + p2 + p3;
#pragma unroll
      for (int d = 1; d < 64; d <<= 1) ss += __shfl_xor(ss, d, 64);
      float Sinv = 1.f / ss;
      if (w == 0) {
        aw[lane] = p0 * Sinv; aw[64 + lane] = p1 * Sinv;
        aw[128 + lane] = p2 * Sinv; aw[192 + lane] = p3 * Sinv;
      }
    } else {
      if (t < 256) aw[t] = 1.f / 256.f;
    }
    __syncthreads();
    {
      // r-phase: 8 groups of 32 atoms; d = output dim (0..127)
      int d = t & 127, grp = t >> 7;
      const unsigned* xc = xl + grp * 32 * 65 + (d >> 1);
      int hi = d & 1;
      const float* ap = aw + grp * 32;
      float r0 = 0.f, r1 = 0.f, r2 = 0.f, r3 = 0.f;
#pragma unroll 4
      for (int n2 = 0; n2 < 32; n2 += 4) {
        unsigned u0 = xc[n2 * 65], u1 = xc[(n2 + 1) * 65];
        unsigned u2 = xc[(n2 + 2) * 65], u3 = xc[(n2 + 3) * 65];
        r0 += ap[n2] * (hi ? hhi(u0) : hlo(u0));
        r1 += ap[n2 + 1] * (hi ? hhi(u1) : hlo(u1));
        r2 += ap[n2 + 2] * (hi ? hhi(u2) : hlo(u2));
        r3 += ap[n2 + 3] * (hi ? hhi(u3) : hlo(u3));
      }
      gates[t] = (r0 + r1) + (r2 + r3);
    }
    __syncthreads();
    if (t < 128) {
      float rd = 0.f;
#pragma unroll
      for (int g = 0; g < 8; g++) rd += gates[g * 128 + t];
      float rp = __shfl_xor(rd, 1, 64);
      if ((t & 1) == 0) qu[64 + (t >> 1)] = packh(rd, rp);
    }
    __syncthreads();
  }
  // memory LSTM gates (split halves; weights loaded once here)
  {
    const uint4* mp = ((const uint4*)(mwihh + (size_t)t0 * 256)) + hi2 * 16;
    float a0 = 0.f, a1 = 0.f, a2 = 0.f, a3 = 0.f;
#pragma unroll
    for (int i = 0; i < 16; i++) {
      uint4 wv = mp[i], qv = q4[hi2 * 16 + i];
      a0 = fdot2u(wv.x, qv.x, a0);
      a1 = fdot2u(wv.y, qv.y, a1);
      a2 = fdot2u(wv.z, qv.z, a2);
      a3 = fdot2u(wv.w, qv.w, a3);
    }
    float mb = (hi2 == 0) ? (mbih[t0] + mbhh[t0]) : 0.f;
    gates[t] = mb + ((a0 + a1) + (a2 + a3));
  }
  __syncthreads();
  if (t < 128) {
    float g0 = gates[t] + gates[512 + t];
    float g2 = gates[256 + t] + gates[768 + t];
    float g3 = gates[384 + t] + gates[896 + t];
    float ig = sigf(g0);
    float gg = ftanh(g2);
    float og = sigf(g3);
    float cx = ig * gg;
    float hx = og * ftanh(cx);
    cst[t] = hx;
    out[64 + s * 128 + t] = hx;
    out[64 + 8192 + s * 128 + t] = cx;
  }
  __syncthreads();
  if (t < 128) {
    float acc = l1b[t];
    const float4* w4 = (const float4*)(l1w + (size_t)t * 128);
    const float4* h4 = (const float4*)cst;
#pragma unroll 8
    for (int k = 0; k < 32; k++) {
      float4 a = w4[k], b = h4[k];
      acc += a.x * b.x + a.y * b.y + a.z * b.z + a.w * b.w;
    }
    red[t] = fmaxf(acc, 0.f) * l3w[t];
  } else if (t < 256) {
    red[t] = 0.f;
  }
  __syncthreads();
  for (int off = 128; off; off >>= 1) {
    if (t < off) red[t] += red[t + off];
    __syncthreads();
  }
  if (t == 0) out[s] = red[0] + l3b[0];
}

// ---------------------------------------------------------------------------
extern "C" void kernel_launch(void* const* d_in, const int* in_sizes, int n_in,
                              void* d_out, int out_size, void* d_ws,
                              size_t ws_size, hipStream_t stream) {
  const float* data       = (const float*)d_in[0];
  const float* lin0_w     = (const float*)d_in[1];
  const float* lin0_b     = (const float*)d_in[2];
  const float* attn_in_w  = (const float*)d_in[3];
  const float* attn_in_b  = (const float*)d_in[4];
  const float* attn_out_w = (const float*)d_in[5];
  const float* attn_out_b = (const float*)d_in[6];
  const float* ln1_g      = (const float*)d_in[7];
  const float* ln1_b      = (const float*)d_in[8];
  const float* ff_w1      = (const float*)d_in[9];
  const float* ff_b1      = (const float*)d_in[10];
  const float* ff_w2      = (const float*)d_in[11];
  const float* ff_b2      = (const float*)d_in[12];
  const float* ln2_g      = (const float*)d_in[13];
  const float* ln2_b      = (const float*)d_in[14];
  const float* s2s_wih    = (const float*)d_in[15];
  const float* s2s_whh    = (const float*)d_in[16];
  const float* s2s_bih    = (const float*)d_in[17];
  const float* s2s_bhh    = (const float*)d_in[18];
  const float* mem_wih    = (const float*)d_in[19];
  const float* mem_bih    = (const float*)d_in[21];
  const float* mem_bhh    = (const float*)d_in[22];
  const float* lin1_w     = (const float*)d_in[23];
  const float* lin1_b     = (const float*)d_in[24];
  const float* lin3_w     = (const float*)d_in[25];
  const float* lin3_b     = (const float*)d_in[26];
  float* out = (float*)d_out;

  char* p = (char*)d_ws;
  float* x = (float*)p;                      p += (size_t)16384 * 128 * 4;
  unsigned short* xb = (unsigned short*)p;   p += (size_t)16384 * 128 * 2;
  unsigned short* wqkv = (unsigned short*)p; p += (size_t)294912 * 2;
  unsigned short* wout = (unsigned short*)p; p += (size_t)98304 * 2;
  unsigned short* w1h = (unsigned short*)p;  p += (size_t)1572864 * 2;
  unsigned short* w2h = (unsigned short*)p;  p += (size_t)1572864 * 2;
  unsigned short* wihh = (unsigned short*)p; p += (size_t)131072 * 2;
  unsigned short* whhh = (unsigned short*)p; p += (size_t)65536 * 2;
  unsigned short* mwihh = (unsigned short*)p; p += (size_t)131072 * 2;

  convw_kernel<<<15104, 256, 0, stream>>>(
      attn_in_w, attn_out_w, ff_w1, ff_w2, s2s_wih, s2s_whh, mem_wih,
      wqkv, wout, w1h, w2h, wihh, whhh, mwihh);
  lin0_kernel<<<8192, 256, 0, stream>>>(data, lin0_w, lin0_b, x, xb);

  for (int l = 0; l < 6; l++) {
    layer_kernel<<<512, 256, 0, stream>>>(
        xb, wqkv + (size_t)l * 49152, attn_in_b + l * 384,
        wout + (size_t)l * 16384, attn_out_b + l * 128,
        ln1_g + l * 128, ln1_b + l * 128,
        w1h + (size_t)l * 262144, ff_b1 + l * 2048,
        w2h + (size_t)l * 262144, ff_b2 + l * 128,
        ln2_g + l * 128, ln2_b + l * 128, x, xb);
  }

  s2s_kernel<<<64, 1024, 0, stream>>>(
      xb, wihh, whhh, s2s_bih, s2s_bhh,
      mwihh, mem_bih, mem_bhh, lin1_w, lin1_b, lin3_w, lin3_b, out);
}

// Round 13
// 405.792 us; speedup vs baseline: 1.1210x; 1.0132x over previous
//
#include <hip/hip_runtime.h>
#include <math.h>

// S=64 seq, B=256 atoms, N=16384, D=128, H=8, HD=16, DFF=2048, NL=6.
// R26 = session-best configuration restored: R22/R23 layer kernels (deep
// weight preloading, swapped-MFMA epilogues, __expf; 48.8us/layer) + R23
// s2s (512 thr, full-row persistent gate weights [VGPR 128 held], __expf,
// 4-acc r-phase; 49.2us). R24/R25's 1024-thread s2s abandoned: compiler
// rematerializes >64 persistent VGPRs of weights at 1024 thr (VGPR=64 both
// rounds), putting 6x weight reload latency on the critical path.

typedef _Float16 __attribute__((ext_vector_type(8))) f16x8;
typedef __attribute__((ext_vector_type(4))) float f32x4;
typedef _Float16 __attribute__((ext_vector_type(2))) h16x2;

__device__ __forceinline__ unsigned short f2h(float f) {
  union { _Float16 h; unsigned short s; } x; x.h = (_Float16)f; return x.s;
}
__device__ __forceinline__ float h2f(unsigned short u) {
  union { unsigned short s; _Float16 h; } x; x.s = u; return (float)x.h;
}
__device__ __forceinline__ unsigned packh(float a, float b) {
  return (unsigned)f2h(a) | ((unsigned)f2h(b) << 16);
}
__device__ __forceinline__ uint2 pk4(float a, float b, float c, float d) {
  return make_uint2(packh(a, b), packh(c, d));
}
__device__ __forceinline__ float hlo(unsigned u) {
  union { unsigned short s; _Float16 h; } x; x.s = (unsigned short)(u & 0xffff);
  return (float)x.h;
}
__device__ __forceinline__ float hhi(unsigned u) {
  union { unsigned short s; _Float16 h; } x; x.s = (unsigned short)(u >> 16);
  return (float)x.h;
}
__device__ __forceinline__ float fdot2u(unsigned a, unsigned b, float c) {
#if __has_builtin(__builtin_amdgcn_fdot2)
  union U { unsigned u; h16x2 h; };
  U x, y; x.u = a; y.u = b;
  return __builtin_amdgcn_fdot2(x.h, y.h, c, false);
#else
  return c + hlo(a) * hlo(b) + hhi(a) * hhi(b);
#endif
}
// fast hardware transcendentals (v_exp_f32)
__device__ __forceinline__ float fexp(float x) { return __expf(x); }
__device__ __forceinline__ float sigf(float x) {
  return 1.f / (1.f + __expf(-x));
}
__device__ __forceinline__ float ftanh(float x) {
  float e = __expf(2.f * x);
  return 1.f - 2.f / (e + 1.f);
}

// async 16B global->LDS; LDS base wave-uniform (+ lane*16 implicit).
__device__ __forceinline__ void gl2lds16(const void* g, void* l) {
  __builtin_amdgcn_global_load_lds(
      (const __attribute__((address_space(1))) unsigned int*)g,
      (__attribute__((address_space(3))) unsigned int*)l, 16, 0, 0);
}

// ---------------------------------------------------------------------------
// weight conversion: everything -> f16, frag-major (see R14 comment).
// ---------------------------------------------------------------------------
__global__ __launch_bounds__(256) void convw_kernel(
    const float* __restrict__ aiw, const float* __restrict__ aow,
    const float* __restrict__ w1, const float* __restrict__ w2,
    const float* __restrict__ wih, const float* __restrict__ whh,
    const float* __restrict__ mwih,
    unsigned short* __restrict__ o0, unsigned short* __restrict__ o1,
    unsigned short* __restrict__ o2, unsigned short* __restrict__ o3,
    unsigned short* __restrict__ o4, unsigned short* __restrict__ o5,
    unsigned short* __restrict__ o6) {
  int i = blockIdx.x * 256 + threadIdx.x;
  if (i < 294912) {
    int l = i / 49152, o = i % 49152;
    int j = o & 7, fr = (o >> 3) & 15, fq = (o >> 7) & 3, ks = (o >> 9) & 3,
        rb = o >> 11;
    o0[i] = f2h(aiw[l * 49152 + (rb * 16 + fr) * 128 + ks * 32 + fq * 8 + j]);
  } else if (i < 393216) {
    int ii = i - 294912;
    int l = ii / 16384, o = ii % 16384;
    int j = o & 7, fr = (o >> 3) & 15, fq = (o >> 7) & 3, ks = (o >> 9) & 3,
        rb = o >> 11;
    o1[ii] = f2h(aow[l * 16384 + (rb * 16 + fr) * 128 + ks * 32 + fq * 8 + j]);
  } else if (i < 1966080) {
    int ii = i - 393216;
    int l = ii >> 18, o = ii & 262143;
    int j = o & 7, fr = (o >> 3) & 15, fq = (o >> 7) & 3, ks = (o >> 9) & 3,
        rb = o >> 11;
    o2[ii] = f2h(w1[l * 262144 + (rb * 16 + fr) * 128 + ks * 32 + fq * 8 + j]);
  } else if (i < 3538944) {
    int ii = i - 1966080;
    int l = ii >> 18, o = ii & 262143;
    int j = o & 7, fr = (o >> 3) & 15, fq = (o >> 7) & 3, ks = (o >> 9) & 63,
        rb = o >> 15;
    o3[ii] = f2h(w2[l * 262144 + (rb * 16 + fr) * 2048 + ks * 32 + fq * 8 + j]);
  } else if (i < 3670016) {
    int j = i - 3538944; o4[j] = f2h(wih[j]);
  } else if (i < 3735552) {
    int j = i - 3670016; o5[j] = f2h(whh[j]);
  } else {
    int j = i - 3735552; o6[j] = f2h(mwih[j]);
  }
}

// ---------------------------------------------------------------------------
// lin0: x = relu(data @ w^T + b), writes fp32 x and f16 xb
// ---------------------------------------------------------------------------
__global__ __launch_bounds__(256) void lin0_kernel(
    const float* __restrict__ data, const float* __restrict__ w,
    const float* __restrict__ b, float* __restrict__ x,
    unsigned short* __restrict__ xb) {
  int i = blockIdx.x * 256 + threadIdx.x;
  int n = i >> 7, d = i & 127;
  float v = b[d] + data[n * 3 + 0] * w[d * 3 + 0]
                 + data[n * 3 + 1] * w[d * 3 + 1]
                 + data[n * 3 + 2] * w[d * 3 + 2];
  v = fmaxf(v, 0.0f);
  x[i] = v;
  xb[i] = f2h(v);
}

// ---------------------------------------------------------------------------
// Fused transformer LAYER: block = (atom b, s-half), 256 threads, 4 waves.
// ---------------------------------------------------------------------------
__global__ __launch_bounds__(256, 2) void layer_kernel(
    const unsigned short* __restrict__ xbg,
    const unsigned short* __restrict__ wqkv, const float* __restrict__ bqkv,
    const unsigned short* __restrict__ wout, const float* __restrict__ bout,
    const float* __restrict__ ln1g, const float* __restrict__ ln1b,
    const unsigned short* __restrict__ w1, const float* __restrict__ b1,
    const unsigned short* __restrict__ w2, const float* __restrict__ b2,
    const float* __restrict__ ln2g, const float* __restrict__ ln2b,
    float* __restrict__ xio, unsigned short* __restrict__ xbo) {
  // shorts: Xs[0,8192) Ks[8192,16384) VT[16384,24576) Qs[24576,28672)
  __shared__ __align__(16) unsigned short SM[28672];
  __shared__ float psum[4][32], psq[4][32];
  __shared__ float2 stats[32];
  __shared__ __align__(16) uint4 zchunk;

  unsigned short* Xs = SM;             // x input -> P slots -> Hs buf0
  unsigned short* Ks = SM + 8192;      // K [s][feat] -> Hs buf1
  unsigned short* VT = SM + 16384;     // V^T [feat][s] -> AOs
  unsigned short* AOs = SM + 16384;    // AO [s][feat] 32x128
  unsigned short* Qs = SM + 24576;     // own-half Q [s][feat] 32x128 -> Xn
  unsigned short* Xn = SM + 24576;

  int tid = threadIdx.x, w = tid >> 6, lane = tid & 63;
  int b = blockIdx.x >> 1, half = blockIdx.x & 1;
  int r4 = lane >> 4, cs = lane & 15;
  int fr = lane & 15, fq = lane >> 4;

  if (tid == 0) zchunk = make_uint4(0u, 0u, 0u, 0u);

  // ---- phase 0: stage full x tile (rows 0..63) ----
#pragma unroll
  for (int i = 0; i < 4; i++) {
    int issue = w * 4 + i;
    int row = issue * 4 + r4;
    int g = cs ^ (row & 7);
    gl2lds16(xbg + (size_t)(row * 256 + b) * 128 + g * 8,
             (char*)Xs + issue * 1024);
  }
  // preload pass-Q weights (8 frags = 32 VGPR) while staging is in flight
  f16x8 wq[4][2];
#pragma unroll
  for (int ks = 0; ks < 4; ks++)
#pragma unroll
    for (int ni = 0; ni < 2; ni++)
      wq[ks][ni] = *(const f16x8*)(wqkv + (size_t)(w * 2 + ni) * 2048 +
                                   ks * 512 + fq * 128 + fr * 8);
  __syncthreads();

  // ---- phase 1: QKV, 3 passes, ONE barrier ----
  // Pass Q (SWAPPED: A=W, B=x): own 32 rows. D[qfeat][s] -> store Qs[s][qfeat]
  {
    f32x4 acc[2][2];
#pragma unroll
    for (int i = 0; i < 2; i++)
#pragma unroll
      for (int j = 0; j < 2; j++) acc[i][j] = (f32x4){0.f, 0.f, 0.f, 0.f};
#pragma unroll
    for (int ks = 0; ks < 4; ks++) {
      f16x8 bx[2];
#pragma unroll
      for (int mi2 = 0; mi2 < 2; mi2++) {
        int row = half * 32 + mi2 * 16 + fr;
        int kq = (ks * 4 + fq) ^ (row & 7);
        bx[mi2] = *(const f16x8*)(Xs + row * 128 + kq * 8);
      }
#pragma unroll
      for (int mi2 = 0; mi2 < 2; mi2++)
#pragma unroll
        for (int ni = 0; ni < 2; ni++)
          acc[mi2][ni] = __builtin_amdgcn_mfma_f32_16x16x32_f16(
              wq[ks][ni], bx[mi2], acc[mi2][ni], 0, 0, 0);
    }
#pragma unroll
    for (int ni = 0; ni < 2; ni++) {
      int fb = (w * 2 + ni) * 16 + fq * 4;
      float4 bv = *(const float4*)&bqkv[fb];
#pragma unroll
      for (int mi2 = 0; mi2 < 2; mi2++) {
        int srow = mi2 * 16 + fr;  // local 0..31
        *(uint2*)(Qs + srow * 128 + (((fb >> 3) ^ (srow & 7)) << 3) +
                  (fb & 7)) =
            pk4(acc[mi2][ni][0] + bv.x, acc[mi2][ni][1] + bv.y,
                acc[mi2][ni][2] + bv.z, acc[mi2][ni][3] + bv.w);
      }
    }
  }
  // Pass K (SWAPPED): full 64 rows. D[kfeat][s] -> store Ks[s][kfeat]
  {
    // preload all 8 K-weight frags
    f16x8 wk[4][2];
#pragma unroll
    for (int ks = 0; ks < 4; ks++)
#pragma unroll
      for (int ni = 0; ni < 2; ni++)
        wk[ks][ni] = *(const f16x8*)(wqkv + (size_t)(8 + w * 2 + ni) * 2048 +
                                     ks * 512 + fq * 128 + fr * 8);
    f32x4 acc[4][2];
#pragma unroll
    for (int i = 0; i < 4; i++)
#pragma unroll
      for (int j = 0; j < 2; j++) acc[i][j] = (f32x4){0.f, 0.f, 0.f, 0.f};
#pragma unroll
    for (int ks = 0; ks < 4; ks++) {
      f16x8 bx[4];
#pragma unroll
      for (int mi = 0; mi < 4; mi++) {
        int row = mi * 16 + fr;
        int kq = (ks * 4 + fq) ^ (row & 7);
        bx[mi] = *(const f16x8*)(Xs + row * 128 + kq * 8);
      }
#pragma unroll
      for (int mi = 0; mi < 4; mi++)
#pragma unroll
        for (int ni = 0; ni < 2; ni++)
          acc[mi][ni] = __builtin_amdgcn_mfma_f32_16x16x32_f16(
              wk[ks][ni], bx[mi], acc[mi][ni], 0, 0, 0);
    }
#pragma unroll
    for (int ni = 0; ni < 2; ni++) {
      int fb = (w * 2 + ni) * 16 + fq * 4;
      float4 bv = *(const float4*)&bqkv[128 + fb];
#pragma unroll
      for (int mi = 0; mi < 4; mi++) {
        int srow = mi * 16 + fr;
        *(uint2*)(Ks + srow * 128 + (((fb >> 3) ^ (srow & 7)) << 3) +
                  (fb & 7)) =
            pk4(acc[mi][ni][0] + bv.x, acc[mi][ni][1] + bv.y,
                acc[mi][ni][2] + bv.z, acc[mi][ni][3] + bv.w);
      }
    }
  }
  // Pass V (UNSWAPPED: A=x, B=W): D[s][vfeat] -> store VT[vfeat][s] packed
  {
    // preload all 8 V-weight frags
    f16x8 wv[4][2];
#pragma unroll
    for (int ks = 0; ks < 4; ks++)
#pragma unroll
      for (int ni = 0; ni < 2; ni++)
        wv[ks][ni] = *(const f16x8*)(wqkv + (size_t)(16 + w * 2 + ni) * 2048 +
                                     ks * 512 + fq * 128 + fr * 8);
    f32x4 acc[4][2];
#pragma unroll
    for (int i = 0; i < 4; i++)
#pragma unroll
      for (int j = 0; j < 2; j++) acc[i][j] = (f32x4){0.f, 0.f, 0.f, 0.f};
#pragma unroll
    for (int ks = 0; ks < 4; ks++) {
      f16x8 ax[4];
#pragma unroll
      for (int mi = 0; mi < 4; mi++) {
        int row = mi * 16 + fr;
        int kq = (ks * 4 + fq) ^ (row & 7);
        ax[mi] = *(const f16x8*)(Xs + row * 128 + kq * 8);
      }
#pragma unroll
      for (int mi = 0; mi < 4; mi++)
#pragma unroll
        for (int ni = 0; ni < 2; ni++)
          acc[mi][ni] = __builtin_amdgcn_mfma_f32_16x16x32_f16(
              ax[mi], wv[ks][ni], acc[mi][ni], 0, 0, 0);
    }
#pragma unroll
    for (int ni = 0; ni < 2; ni++) {
      int feat = (w * 2 + ni) * 16 + fr;
      float bv = bqkv[256 + feat];
#pragma unroll
      for (int mi = 0; mi < 4; mi++) {
        int sb = mi * 16 + fq * 4;
        *(uint2*)(VT + feat * 64 + (((sb >> 3) ^ (feat & 7)) << 3) +
                  (sb & 7)) =
            pk4(acc[mi][ni][0] + bv, acc[mi][ni][1] + bv,
                acc[mi][ni][2] + bv, acc[mi][ni][3] + bv);
      }
    }
  }
  // preload Wout frags (8 = 32 VGPR) -- consumed in phase 4, issued here so
  // L2 latency hides under the attention phase.
  f16x8 wo[4][2];
#pragma unroll
  for (int ks = 0; ks < 4; ks++)
#pragma unroll
    for (int ni = 0; ni < 2; ni++)
      wo[ks][ni] = *(const f16x8*)(wout + (size_t)(w * 2 + ni) * 2048 +
                                   ks * 512 + fq * 128 + fr * 8);
  __syncthreads();  // QKV published; Xs reads done -> Xs reusable as P slots

  // ---- attention: wave w -> heads {2w, 2w+1}, own 32 rows; P in Xs ----
  f32x4 po[2][2];
#pragma unroll
  for (int i = 0; i < 2; i++)
#pragma unroll
    for (int j = 0; j < 2; j++) po[i][j] = (f32x4){0.f, 0.f, 0.f, 0.f};
  {
    unsigned short* Pb = Xs + w * 2048;  // 4KB wave-private slot
#pragma unroll
    for (int hi = 0; hi < 2; hi++) {
      int h = w * 2 + hi;
      f16x8 afH[2], bfH[4];
#pragma unroll
      for (int mi2 = 0; mi2 < 2; mi2++) {
        int qrow = mi2 * 16 + fr;  // local 0..31
        const unsigned short* pa =
            (fq < 2) ? (Qs + qrow * 128 + (((h * 2 + fq) ^ (qrow & 7)) << 3))
                     : (const unsigned short*)&zchunk;
        afH[mi2] = *(const f16x8*)pa;
      }
#pragma unroll
      for (int ti = 0; ti < 4; ti++) {
        int trow = ti * 16 + fr;
        const unsigned short* pb =
            (fq < 2) ? (Ks + trow * 128 + (((h * 2 + fq) ^ (trow & 7)) << 3))
                     : (const unsigned short*)&zchunk;
        bfH[ti] = *(const f16x8*)pb;
      }
      f32x4 sc[2][4];
#pragma unroll
      for (int i = 0; i < 2; i++)
#pragma unroll
        for (int j = 0; j < 4; j++) sc[i][j] = (f32x4){0.f, 0.f, 0.f, 0.f};
#pragma unroll
      for (int mi2 = 0; mi2 < 2; mi2++)
#pragma unroll
        for (int ti = 0; ti < 4; ti++)
          sc[mi2][ti] = __builtin_amdgcn_mfma_f32_16x16x32_f16(
              afH[mi2], bfH[ti], sc[mi2][ti], 0, 0, 0);
#pragma unroll
      for (int mi2 = 0; mi2 < 2; mi2++) {
#pragma unroll
        for (int r = 0; r < 4; r++) {
          float m = -1e30f;
#pragma unroll
          for (int ti = 0; ti < 4; ti++) m = fmaxf(m, sc[mi2][ti][r]);
          m = fmaxf(m, __shfl_xor(m, 1, 64));
          m = fmaxf(m, __shfl_xor(m, 2, 64));
          m = fmaxf(m, __shfl_xor(m, 4, 64));
          m = fmaxf(m, __shfl_xor(m, 8, 64));
          m *= 0.25f;
          float ss = 0.f;
#pragma unroll
          for (int ti = 0; ti < 4; ti++) {
            float p = fexp(sc[mi2][ti][r] * 0.25f - m);
            sc[mi2][ti][r] = p;
            ss += p;
          }
          ss += __shfl_xor(ss, 1, 64);
          ss += __shfl_xor(ss, 2, 64);
          ss += __shfl_xor(ss, 4, 64);
          ss += __shfl_xor(ss, 8, 64);
          float inv = 1.f / ss;
          int prow = mi2 * 16 + fq * 4 + r;  // local 0..31
#pragma unroll
          for (int ti = 0; ti < 4; ti++) {
            int t = ti * 16 + fr;
            Pb[prow * 64 + (((t >> 3) ^ (prow & 7)) << 3) + (t & 7)] =
                f2h(sc[mi2][ti][r] * inv);
          }
        }
      }
      // PV SWAPPED: A=VT frag, B=P frag -> D[vfeat][s]
#pragma unroll
      for (int ks2 = 0; ks2 < 2; ks2++) {
        f16x8 bp[2], avt;
#pragma unroll
        for (int si2 = 0; si2 < 2; si2++) {
          int prow = si2 * 16 + fr;
          int kq = (ks2 * 4 + fq) ^ (prow & 7);
          bp[si2] = *(const f16x8*)(Pb + prow * 64 + kq * 8);
        }
        {
          int vrow = h * 16 + fr;
          int kq = (ks2 * 4 + fq) ^ (vrow & 7);
          avt = *(const f16x8*)(VT + vrow * 64 + kq * 8);
        }
#pragma unroll
        for (int si2 = 0; si2 < 2; si2++)
          po[hi][si2] = __builtin_amdgcn_mfma_f32_16x16x32_f16(
              avt, bp[si2], po[hi][si2], 0, 0, 0);
      }
    }
  }
  __syncthreads();  // all PV reads of VT done -> VT reusable as AOs
  // AO store: lane holds 4 consecutive vfeat at fixed s -> b64
#pragma unroll
  for (int hi = 0; hi < 2; hi++) {
    int fb = (w * 2 + hi) * 16 + fq * 4;
#pragma unroll
    for (int si2 = 0; si2 < 2; si2++) {
      int srow = si2 * 16 + fr;
      *(uint2*)(AOs + srow * 128 + (((fb >> 3) ^ (srow & 7)) << 3) +
                (fb & 7)) =
          pk4(po[hi][si2][0], po[hi][si2][1], po[hi][si2][2], po[hi][si2][3]);
    }
  }
  __syncthreads();  // AO published

  // ---- phase 4 (SWAPPED): v = x + ao @ Wout^T + bias ; LN1 -> Xn ----
  {
    f32x4 acc[2][2];
#pragma unroll
    for (int i = 0; i < 2; i++)
#pragma unroll
      for (int j = 0; j < 2; j++) acc[i][j] = (f32x4){0.f, 0.f, 0.f, 0.f};
#pragma unroll
    for (int ks = 0; ks < 4; ks++) {
      f16x8 bao[2];
#pragma unroll
      for (int mi2 = 0; mi2 < 2; mi2++) {
        int row = mi2 * 16 + fr;
        int kq = (ks * 4 + fq) ^ (row & 7);
        bao[mi2] = *(const f16x8*)(AOs + row * 128 + kq * 8);
      }
#pragma unroll
      for (int mi2 = 0; mi2 < 2; mi2++)
#pragma unroll
        for (int ni = 0; ni < 2; ni++)
          acc[mi2][ni] = __builtin_amdgcn_mfma_f32_16x16x32_f16(
              wo[ks][ni], bao[mi2], acc[mi2][ni], 0, 0, 0);
    }
    // lane: s = mi2*16+fr (local), feats = (w*2+ni)*16 + fq*4 + r
    float v4[2][2][4];  // [ni][mi2][r]
    float psA[2] = {0.f, 0.f}, psQ[2] = {0.f, 0.f};
#pragma unroll
    for (int ni = 0; ni < 2; ni++) {
      int fb = (w * 2 + ni) * 16 + fq * 4;
      float4 bv = *(const float4*)&bout[fb];
#pragma unroll
      for (int mi2 = 0; mi2 < 2; mi2++) {
        int rowg = half * 32 + mi2 * 16 + fr;
        float4 rs = *(const float4*)&xio[(size_t)(rowg * 256 + b) * 128 + fb];
        float t0 = acc[mi2][ni][0] + bv.x + rs.x;
        float t1 = acc[mi2][ni][1] + bv.y + rs.y;
        float t2 = acc[mi2][ni][2] + bv.z + rs.z;
        float t3 = acc[mi2][ni][3] + bv.w + rs.w;
        v4[ni][mi2][0] = t0; v4[ni][mi2][1] = t1;
        v4[ni][mi2][2] = t2; v4[ni][mi2][3] = t3;
        psA[mi2] += (t0 + t1) + (t2 + t3);
        psQ[mi2] += (t0 * t0 + t1 * t1) + (t2 * t2 + t3 * t3);
      }
    }
#pragma unroll
    for (int mi2 = 0; mi2 < 2; mi2++) {
      psA[mi2] += __shfl_xor(psA[mi2], 16, 64);
      psA[mi2] += __shfl_xor(psA[mi2], 32, 64);
      psQ[mi2] += __shfl_xor(psQ[mi2], 16, 64);
      psQ[mi2] += __shfl_xor(psQ[mi2], 32, 64);
    }
    if (fq == 0) {
#pragma unroll
      for (int mi2 = 0; mi2 < 2; mi2++) {
        psum[w][mi2 * 16 + fr] = psA[mi2];
        psq[w][mi2 * 16 + fr] = psQ[mi2];
      }
    }
    __syncthreads();  // A
    if (tid < 32) {
      float S = 0.f, Q = 0.f;
#pragma unroll
      for (int ww = 0; ww < 4; ww++) { S += psum[ww][tid]; Q += psq[ww][tid]; }
      float m = S * (1.f / 128.f);
      float var = Q * (1.f / 128.f) - m * m;
      stats[tid] = make_float2(m, rsqrtf(var + 1e-5f));
    }
    __syncthreads();  // B
#pragma unroll
    for (int ni = 0; ni < 2; ni++) {
      int fb = (w * 2 + ni) * 16 + fq * 4;
      float4 g4 = *(const float4*)&ln1g[fb];
      float4 b4 = *(const float4*)&ln1b[fb];
#pragma unroll
      for (int mi2 = 0; mi2 < 2; mi2++) {
        int srow = mi2 * 16 + fr;
        float2 st = stats[srow];
        float y0 = (v4[ni][mi2][0] - st.x) * st.y * g4.x + b4.x;
        float y1 = (v4[ni][mi2][1] - st.x) * st.y * g4.y + b4.y;
        float y2 = (v4[ni][mi2][2] - st.x) * st.y * g4.z + b4.z;
        float y3 = (v4[ni][mi2][3] - st.x) * st.y * g4.w + b4.w;
        *(uint2*)(Xn + srow * 128 + (((fb >> 3) ^ (srow & 7)) << 3) +
                  (fb & 7)) = pk4(y0, y1, y2, y3);
      }
    }
  }
  __syncthreads();  // C: LN1 out published; Xs+Ks dead -> Hs dbuf (2x16KB)

  // hoisted FFN x fragments (B-operand; local 32 rows)
  f16x8 xfragF[4][2];
#pragma unroll
  for (int ks = 0; ks < 4; ks++)
#pragma unroll
    for (int mi2 = 0; mi2 < 2; mi2++) {
      int rowl = mi2 * 16 + fr;
      int kq = (ks * 4 + fq) ^ (rowl & 7);
      xfragF[ks][mi2] = *(const f16x8*)(Xn + rowl * 128 + kq * 8);
    }

  // ---- FFN (SWAPPED): 8 chunks x 256 hidden. H stored [s][hcol] packed.
  f32x4 acc2[2][2];
#pragma unroll
  for (int i = 0; i < 2; i++)
#pragma unroll
    for (int j = 0; j < 2; j++) acc2[i][j] = (f32x4){0.f, 0.f, 0.f, 0.f};

  for (int c = 0; c < 8; c++) {
    unsigned short* Hcur = SM + (c & 1) * 8192;
    // preload full ff1 weight set for this chunk (16 frags = 64 VGPR)
    f16x8 aw1[4][4];
#pragma unroll
    for (int ks = 0; ks < 4; ks++)
#pragma unroll
      for (int ni = 0; ni < 4; ni++)
        aw1[ks][ni] = *(const f16x8*)(w1 + (size_t)(c * 16 + w * 4 + ni) *
                                              2048 +
                                      ks * 512 + fq * 128 + fr * 8);
    f32x4 acc1[2][4];
#pragma unroll
    for (int i = 0; i < 2; i++)
#pragma unroll
      for (int j = 0; j < 4; j++) acc1[i][j] = (f32x4){0.f, 0.f, 0.f, 0.f};
#pragma unroll
    for (int ks = 0; ks < 4; ks++)
#pragma unroll
      for (int mi2 = 0; mi2 < 2; mi2++)
#pragma unroll
        for (int ni = 0; ni < 4; ni++)
          acc1[mi2][ni] = __builtin_amdgcn_mfma_f32_16x16x32_f16(
              aw1[ks][ni], xfragF[ks][mi2], acc1[mi2][ni], 0, 0, 0);
#pragma unroll
    for (int ni = 0; ni < 4; ni++) {
      int hb = (w * 4 + ni) * 16 + fq * 4;  // 0..255
      float4 bv = *(const float4*)&b1[c * 256 + hb];
#pragma unroll
      for (int mi2 = 0; mi2 < 2; mi2++) {
        int srow = mi2 * 16 + fr;
        *(uint2*)(Hcur + srow * 256 + (((hb >> 3) ^ (srow & 7)) << 3) +
                  (hb & 7)) =
            pk4(fmaxf(acc1[mi2][ni][0] + bv.x, 0.f),
                fmaxf(acc1[mi2][ni][1] + bv.y, 0.f),
                fmaxf(acc1[mi2][ni][2] + bv.z, 0.f),
                fmaxf(acc1[mi2][ni][3] + bv.w, 0.f));
      }
    }
    // preload full ff2 weight set BEFORE the barrier (16 frags = 64 VGPR);
    // their ~200cy L2 latency hides under the barrier wait.
    f16x8 aw2[8][2];
#pragma unroll
    for (int ks2 = 0; ks2 < 8; ks2++)
#pragma unroll
      for (int ni = 0; ni < 2; ni++)
        aw2[ks2][ni] = *(const f16x8*)(w2 + (size_t)(w * 2 + ni) * 32768 +
                                       (c * 8 + ks2) * 512 + fq * 128 +
                                       fr * 8);
    __syncthreads();  // Hcur visible; dbuf -> 1 barrier/chunk
#pragma unroll
    for (int ks2 = 0; ks2 < 8; ks2++) {
      f16x8 bh[2];
#pragma unroll
      for (int mi2 = 0; mi2 < 2; mi2++) {
        int row = mi2 * 16 + fr;
        int kq = (ks2 * 4 + fq) ^ (row & 7);
        bh[mi2] = *(const f16x8*)(Hcur + row * 256 + kq * 8);
      }
#pragma unroll
      for (int mi2 = 0; mi2 < 2; mi2++)
#pragma unroll
        for (int ni = 0; ni < 2; ni++)
          acc2[mi2][ni] = __builtin_amdgcn_mfma_f32_16x16x32_f16(
              aw2[ks2][ni], bh[mi2], acc2[mi2][ni], 0, 0, 0);
    }
  }

  // ---- FFN epilogue: +b2 + residual (Xn), LN2, write global ----
  {
    float v4[2][2][4];  // [ni][mi2][r]
    float psA[2] = {0.f, 0.f}, psQ[2] = {0.f, 0.f};
#pragma unroll
    for (int ni = 0; ni < 2; ni++) {
      int fb = (w * 2 + ni) * 16 + fq * 4;
      float4 bv = *(const float4*)&b2[fb];
#pragma unroll
      for (int mi2 = 0; mi2 < 2; mi2++) {
        int srow = mi2 * 16 + fr;
        uint2 rz = *(const uint2*)(Xn + srow * 128 +
                                   (((fb >> 3) ^ (srow & 7)) << 3) + (fb & 7));
        float t0 = acc2[mi2][ni][0] + bv.x + hlo(rz.x);
        float t1 = acc2[mi2][ni][1] + bv.y + hhi(rz.x);
        float t2 = acc2[mi2][ni][2] + bv.z + hlo(rz.y);
        float t3 = acc2[mi2][ni][3] + bv.w + hhi(rz.y);
        v4[ni][mi2][0] = t0; v4[ni][mi2][1] = t1;
        v4[ni][mi2][2] = t2; v4[ni][mi2][3] = t3;
        psA[mi2] += (t0 + t1) + (t2 + t3);
        psQ[mi2] += (t0 * t0 + t1 * t1) + (t2 * t2 + t3 * t3);
      }
    }
#pragma unroll
    for (int mi2 = 0; mi2 < 2; mi2++) {
      psA[mi2] += __shfl_xor(psA[mi2], 16, 64);
      psA[mi2] += __shfl_xor(psA[mi2], 32, 64);
      psQ[mi2] += __shfl_xor(psQ[mi2], 16, 64);
      psQ[mi2] += __shfl_xor(psQ[mi2], 32, 64);
    }
    if (fq == 0) {
#pragma unroll
      for (int mi2 = 0; mi2 < 2; mi2++) {
        psum[w][mi2 * 16 + fr] = psA[mi2];
        psq[w][mi2 * 16 + fr] = psQ[mi2];
      }
    }
    __syncthreads();
    if (tid < 32) {
      float S = 0.f, Q = 0.f;
#pragma unroll
      for (int ww = 0; ww < 4; ww++) { S += psum[ww][tid]; Q += psq[ww][tid]; }
      float m = S * (1.f / 128.f);
      float var = Q * (1.f / 128.f) - m * m;
      stats[tid] = make_float2(m, rsqrtf(var + 1e-5f));
    }
    __syncthreads();
#pragma unroll
    for (int ni = 0; ni < 2; ni++) {
      int fb = (w * 2 + ni) * 16 + fq * 4;
      float4 g4 = *(const float4*)&ln2g[fb];
      float4 b4 = *(const float4*)&ln2b[fb];
#pragma unroll
      for (int mi2 = 0; mi2 < 2; mi2++) {
        int srow = mi2 * 16 + fr;
        float2 st = stats[srow];
        float y0 = (v4[ni][mi2][0] - st.x) * st.y * g4.x + b4.x;
        float y1 = (v4[ni][mi2][1] - st.x) * st.y * g4.y + b4.y;
        float y2 = (v4[ni][mi2][2] - st.x) * st.y * g4.z + b4.z;
        float y3 = (v4[ni][mi2][3] - st.x) * st.y * g4.w + b4.w;
        size_t o = (size_t)((half * 32 + srow) * 256 + b) * 128 + fb;
        *(float4*)&xio[o] = make_float4(y0, y1, y2, y3);
        *(uint2*)&xbo[o] = pk4(y0, y1, y2, y3);
      }
    }
  }
}

// ---------------------------------------------------------------------------
// Set2Set (6 steps) + memory LSTM + lin1 + lin3. One 512-thread block per
// segment. Input xb is f16 (direct copy into LDS).
// R23 version: full-row persistent weights (held at 512 thr), __expf
// transcendentals, 4-way ILP r-phase.
// ---------------------------------------------------------------------------
__global__ __launch_bounds__(512, 1) void s2s_kernel(
    const unsigned short* __restrict__ xb,
    const unsigned short* __restrict__ wihh,
    const unsigned short* __restrict__ whhh,
    const float* __restrict__ bih, const float* __restrict__ bhh,
    const unsigned short* __restrict__ mwihh,
    const float* __restrict__ mbih, const float* __restrict__ mbhh,
    const float* __restrict__ l1w, const float* __restrict__ l1b,
    const float* __restrict__ l3w, const float* __restrict__ l3b,
    float* __restrict__ out) {
  __shared__ __align__(16) unsigned xl[256 * 65];
  __shared__ __align__(16) unsigned qu[128];
  __shared__ __align__(16) float cst[128];
  __shared__ __align__(16) float gates[512];
  __shared__ __align__(16) float red[256];
  __shared__ __align__(16) float aw[256];
  int s = blockIdx.x, t = threadIdx.x, lane = t & 63, w = t >> 6;

  uint4 wreg[32], ureg[16];
  {
    const uint4* wp = (const uint4*)(wihh + (size_t)t * 256);
#pragma unroll
    for (int i = 0; i < 32; i++) wreg[i] = wp[i];
    const uint4* up = (const uint4*)(whhh + (size_t)t * 128);
#pragma unroll
    for (int i = 0; i < 16; i++) ureg[i] = up[i];
  }

  const uint4* xs4 = (const uint4*)(xb + (size_t)s * 32768);
#pragma unroll
  for (int it = 0; it < 8; it++) {
    int f = it * 512 + t;
    uint4 v = xs4[f];
    int n = f >> 4, jc = (f & 15) * 4;
    unsigned* dst = xl + n * 65 + jc;
    dst[0] = v.x; dst[1] = v.y; dst[2] = v.z; dst[3] = v.w;
  }
  if (t < 128) cst[t] = 0.f;
  __syncthreads();

  const uint4* q4 = (const uint4*)qu;
  float bsum = bih[t] + bhh[t];

  for (int step = 0; step < 6; step++) {
    if (step > 0) {
      float a0 = 0.f, a1 = 0.f, a2 = 0.f, a3 = 0.f;
#pragma unroll
      for (int i = 0; i < 16; i++) {
        uint4 qv = q4[i];
        a0 = fdot2u(wreg[i].x, qv.x, a0);
        a1 = fdot2u(wreg[i].y, qv.y, a1);
        a2 = fdot2u(wreg[i].z, qv.z, a2);
        a3 = fdot2u(wreg[i].w, qv.w, a3);
        a0 = fdot2u(ureg[i].x, qv.x, a0);
        a1 = fdot2u(ureg[i].y, qv.y, a1);
        a2 = fdot2u(ureg[i].z, qv.z, a2);
        a3 = fdot2u(ureg[i].w, qv.w, a3);
      }
#pragma unroll
      for (int i = 16; i < 32; i++) {
        uint4 qv = q4[i];
        a0 = fdot2u(wreg[i].x, qv.x, a0);
        a1 = fdot2u(wreg[i].y, qv.y, a1);
        a2 = fdot2u(wreg[i].z, qv.z, a2);
        a3 = fdot2u(wreg[i].w, qv.w, a3);
      }
      gates[t] = bsum + ((a0 + a1) + (a2 + a3));
    } else {
      gates[t] = bsum;
    }
    __syncthreads();
    if (t < 128) {
      float ig = sigf(gates[t]), fg = sigf(gates[128 + t]);
      float gg = ftanh(gates[256 + t]), og = sigf(gates[384 + t]);
      float cn = fg * cst[t] + ig * gg;
      cst[t] = cn;
      float hn = og * ftanh(cn);
      float hp = __shfl_xor(hn, 1, 64);
      if ((t & 1) == 0) qu[t >> 1] = packh(hn, hp);
    }
    __syncthreads();
    if (step > 0) {
      int n = t >> 1, p = t & 1;
      const unsigned* xr = xl + n * 65 + p * 32;
      float e0 = 0.f, e1 = 0.f;
#pragma unroll 8
      for (int i = 0; i < 32; i += 2) {
        e0 = fdot2u(xr[i], qu[p * 32 + i], e0);
        e1 = fdot2u(xr[i + 1], qu[p * 32 + i + 1], e1);
      }
      float e = e0 + e1;
      e += __shfl_xor(e, 1, 64);
      if (p == 0) red[n] = e;
      __syncthreads();
      float v0 = red[lane], v1 = red[64 + lane];
      float v2 = red[128 + lane], v3 = red[192 + lane];
      float m = fmaxf(fmaxf(v0, v1), fmaxf(v2, v3));
#pragma unroll
      for (int d = 1; d < 64; d <<= 1) m = fmaxf(m, __shfl_xor(m, d, 64));
      float p0 = fexp(v0 - m), p1 = fexp(v1 - m);
      float p2 = fexp(v2 - m), p3 = fexp(v3 - m);
      float ss = p0 + p1 + p2 + p3;
#pragma unroll
      for (int d = 1; d < 64; d <<= 1) ss += __shfl_xor(ss, d, 64);
      float Sinv = 1.f / ss;
      if (w == 0) {
        aw[lane] = p0 * Sinv; aw[64 + lane] = p1 * Sinv;
        aw[128 + lane] = p2 * Sinv; aw[192 + lane] = p3 * Sinv;
      }
    } else {
      if (t < 256) aw[t] = 1.f / 256.f;
    }
    __syncthreads();
    {
      int d = t & 127, grp = t >> 7;
      const unsigned* xc = xl + grp * 64 * 65 + (d >> 1);
      int hi = d & 1;
      const float* ap = aw + grp * 64;
      // 4 independent accumulators: chain 16, loads 4-deep in flight
      float r0 = 0.f, r1 = 0.f, r2 = 0.f, r3 = 0.f;
#pragma unroll 4
      for (int n2 = 0; n2 < 64; n2 += 4) {
        unsigned u0 = xc[n2 * 65], u1 = xc[(n2 + 1) * 65];
        unsigned u2 = xc[(n2 + 2) * 65], u3 = xc[(n2 + 3) * 65];
        r0 += ap[n2] * (hi ? hhi(u0) : hlo(u0));
        r1 += ap[n2 + 1] * (hi ? hhi(u1) : hlo(u1));
        r2 += ap[n2 + 2] * (hi ? hhi(u2) : hlo(u2));
        r3 += ap[n2 + 3] * (hi ? hhi(u3) : hlo(u3));
      }
      gates[t] = (r0 + r1) + (r2 + r3);
    }
    __syncthreads();
    if (t < 128) {
      float rd = gates[t] + gates[128 + t] + gates[256 + t] + gates[384 + t];
      float rp = __shfl_xor(rd, 1, 64);
      if ((t & 1) == 0) qu[64 + (t >> 1)] = packh(rd, rp);
    }
    __syncthreads();
  }
  {
    float a0 = 0.f, a1 = 0.f, a2 = 0.f, a3 = 0.f;
    const uint4* mp = (const uint4*)(mwihh + (size_t)t * 256);
#pragma unroll 8
    for (int i = 0; i < 32; i++) {
      uint4 wv = mp[i], qv = q4[i];
      a0 = fdot2u(wv.x, qv.x, a0);
      a1 = fdot2u(wv.y, qv.y, a1);
      a2 = fdot2u(wv.z, qv.z, a2);
      a3 = fdot2u(wv.w, qv.w, a3);
    }
    gates[t] = mbih[t] + mbhh[t] + ((a0 + a1) + (a2 + a3));
  }
  __syncthreads();
  if (t < 128) {
    float ig = sigf(gates[t]);
    float gg = ftanh(gates[256 + t]);
    float og = sigf(gates[384 + t]);
    float cx = ig * gg;
    float hx = og * ftanh(cx);
    cst[t] = hx;
    out[64 + s * 128 + t] = hx;
    out[64 + 8192 + s * 128 + t] = cx;
  }
  __syncthreads();
  if (t < 128) {
    float acc = l1b[t];
    const float4* w4 = (const float4*)(l1w + (size_t)t * 128);
    const float4* h4 = (const float4*)cst;
#pragma unroll 8
    for (int k = 0; k < 32; k++) {
      float4 a = w4[k], b = h4[k];
      acc += a.x * b.x + a.y * b.y + a.z * b.z + a.w * b.w;
    }
    red[t] = fmaxf(acc, 0.f) * l3w[t];
  } else if (t < 256) {
    red[t] = 0.f;
  }
  __syncthreads();
  for (int off = 128; off; off >>= 1) {
    if (t < off) red[t] += red[t + off];
    __syncthreads();
  }
  if (t == 0) out[s] = red[0] + l3b[0];
}

// ---------------------------------------------------------------------------
extern "C" void kernel_launch(void* const* d_in, const int* in_sizes, int n_in,
                              void* d_out, int out_size, void* d_ws,
                              size_t ws_size, hipStream_t stream) {
  const float* data       = (const float*)d_in[0];
  const float* lin0_w     = (const float*)d_in[1];
  const float* lin0_b     = (const float*)d_in[2];
  const float* attn_in_w  = (const float*)d_in[3];
  const float* attn_in_b  = (const float*)d_in[4];
  const float* attn_out_w = (const float*)d_in[5];
  const float* attn_out_b = (const float*)d_in[6];
  const float* ln1_g      = (const float*)d_in[7];
  const float* ln1_b      = (const float*)d_in[8];
  const float* ff_w1      = (const float*)d_in[9];
  const float* ff_b1      = (const float*)d_in[10];
  const float* ff_w2      = (const float*)d_in[11];
  const float* ff_b2      = (const float*)d_in[12];
  const float* ln2_g      = (const float*)d_in[13];
  const float* ln2_b      = (const float*)d_in[14];
  const float* s2s_wih    = (const float*)d_in[15];
  const float* s2s_whh    = (const float*)d_in[16];
  const float* s2s_bih    = (const float*)d_in[17];
  const float* s2s_bhh    = (const float*)d_in[18];
  const float* mem_wih    = (const float*)d_in[19];
  const float* mem_bih    = (const float*)d_in[21];
  const float* mem_bhh    = (const float*)d_in[22];
  const float* lin1_w     = (const float*)d_in[23];
  const float* lin1_b     = (const float*)d_in[24];
  const float* lin3_w     = (const float*)d_in[25];
  const float* lin3_b     = (const float*)d_in[26];
  float* out = (float*)d_out;

  char* p = (char*)d_ws;
  float* x = (float*)p;                      p += (size_t)16384 * 128 * 4;
  unsigned short* xb = (unsigned short*)p;   p += (size_t)16384 * 128 * 2;
  unsigned short* wqkv = (unsigned short*)p; p += (size_t)294912 * 2;
  unsigned short* wout = (unsigned short*)p; p += (size_t)98304 * 2;
  unsigned short* w1h = (unsigned short*)p;  p += (size_t)1572864 * 2;
  unsigned short* w2h = (unsigned short*)p;  p += (size_t)1572864 * 2;
  unsigned short* wihh = (unsigned short*)p; p += (size_t)131072 * 2;
  unsigned short* whhh = (unsigned short*)p; p += (size_t)65536 * 2;
  unsigned short* mwihh = (unsigned short*)p; p += (size_t)131072 * 2;

  convw_kernel<<<15104, 256, 0, stream>>>(
      attn_in_w, attn_out_w, ff_w1, ff_w2, s2s_wih, s2s_whh, mem_wih,
      wqkv, wout, w1h, w2h, wihh, whhh, mwihh);
  lin0_kernel<<<8192, 256, 0, stream>>>(data, lin0_w, lin0_b, x, xb);

  for (int l = 0; l < 6; l++) {
    layer_kernel<<<512, 256, 0, stream>>>(
        xb, wqkv + (size_t)l * 49152, attn_in_b + l * 384,
        wout + (size_t)l * 16384, attn_out_b + l * 128,
        ln1_g + l * 128, ln1_b + l * 128,
        w1h + (size_t)l * 262144, ff_b1 + l * 2048,
        w2h + (size_t)l * 262144, ff_b2 + l * 128,
        ln2_g + l * 128, ln2_b + l * 128, x, xb);
  }

  s2s_kernel<<<64, 512, 0, stream>>>(
      xb, wihh, whhh, s2s_bih, s2s_bhh,
      mwihh, mem_bih, mem_bhh, lin1_w, lin1_b, lin3_w, lin3_b, out);
}

// Round 14
// 404.870 us; speedup vs baseline: 1.1236x; 1.0023x over previous
//
#include <hip/hip_runtime.h>
#include <math.h>

// S=64 seq, B=256 atoms, N=16384, D=128, H=8, HD=16, DFF=2048, NL=6.
// R27 = R26 (session-best: layers 48.8us w/ deep weight preloading +
// swapped-MFMA epilogues + __expf; s2s 49us w/ persistent full-row gate
// weights) + convw/lin0 MERGED into one prep_kernel (they are mutually
// independent; merging removes one dispatch boundary and fills CU tail).

typedef _Float16 __attribute__((ext_vector_type(8))) f16x8;
typedef __attribute__((ext_vector_type(4))) float f32x4;
typedef _Float16 __attribute__((ext_vector_type(2))) h16x2;

__device__ __forceinline__ unsigned short f2h(float f) {
  union { _Float16 h; unsigned short s; } x; x.h = (_Float16)f; return x.s;
}
__device__ __forceinline__ float h2f(unsigned short u) {
  union { unsigned short s; _Float16 h; } x; x.s = u; return (float)x.h;
}
__device__ __forceinline__ unsigned packh(float a, float b) {
  return (unsigned)f2h(a) | ((unsigned)f2h(b) << 16);
}
__device__ __forceinline__ uint2 pk4(float a, float b, float c, float d) {
  return make_uint2(packh(a, b), packh(c, d));
}
__device__ __forceinline__ float hlo(unsigned u) {
  union { unsigned short s; _Float16 h; } x; x.s = (unsigned short)(u & 0xffff);
  return (float)x.h;
}
__device__ __forceinline__ float hhi(unsigned u) {
  union { unsigned short s; _Float16 h; } x; x.s = (unsigned short)(u >> 16);
  return (float)x.h;
}
__device__ __forceinline__ float fdot2u(unsigned a, unsigned b, float c) {
#if __has_builtin(__builtin_amdgcn_fdot2)
  union U { unsigned u; h16x2 h; };
  U x, y; x.u = a; y.u = b;
  return __builtin_amdgcn_fdot2(x.h, y.h, c, false);
#else
  return c + hlo(a) * hlo(b) + hhi(a) * hhi(b);
#endif
}
// fast hardware transcendentals (v_exp_f32)
__device__ __forceinline__ float fexp(float x) { return __expf(x); }
__device__ __forceinline__ float sigf(float x) {
  return 1.f / (1.f + __expf(-x));
}
__device__ __forceinline__ float ftanh(float x) {
  float e = __expf(2.f * x);
  return 1.f - 2.f / (e + 1.f);
}

// async 16B global->LDS; LDS base wave-uniform (+ lane*16 implicit).
__device__ __forceinline__ void gl2lds16(const void* g, void* l) {
  __builtin_amdgcn_global_load_lds(
      (const __attribute__((address_space(1))) unsigned int*)g,
      (__attribute__((address_space(3))) unsigned int*)l, 16, 0, 0);
}

// ---------------------------------------------------------------------------
// prep: weight conversion -> f16 frag-major (R14 layout) + lin0 fused.
// ranges: [0, 3866624) weights; [3866624, 5963776) lin0 (16384x128).
// ---------------------------------------------------------------------------
__global__ __launch_bounds__(256) void prep_kernel(
    const float* __restrict__ aiw, const float* __restrict__ aow,
    const float* __restrict__ w1, const float* __restrict__ w2,
    const float* __restrict__ wih, const float* __restrict__ whh,
    const float* __restrict__ mwih,
    unsigned short* __restrict__ o0, unsigned short* __restrict__ o1,
    unsigned short* __restrict__ o2, unsigned short* __restrict__ o3,
    unsigned short* __restrict__ o4, unsigned short* __restrict__ o5,
    unsigned short* __restrict__ o6,
    const float* __restrict__ data, const float* __restrict__ l0w,
    const float* __restrict__ l0b, float* __restrict__ x,
    unsigned short* __restrict__ xb) {
  int i = blockIdx.x * 256 + threadIdx.x;
  if (i < 294912) {
    int l = i / 49152, o = i % 49152;
    int j = o & 7, fr = (o >> 3) & 15, fq = (o >> 7) & 3, ks = (o >> 9) & 3,
        rb = o >> 11;
    o0[i] = f2h(aiw[l * 49152 + (rb * 16 + fr) * 128 + ks * 32 + fq * 8 + j]);
  } else if (i < 393216) {
    int ii = i - 294912;
    int l = ii / 16384, o = ii % 16384;
    int j = o & 7, fr = (o >> 3) & 15, fq = (o >> 7) & 3, ks = (o >> 9) & 3,
        rb = o >> 11;
    o1[ii] = f2h(aow[l * 16384 + (rb * 16 + fr) * 128 + ks * 32 + fq * 8 + j]);
  } else if (i < 1966080) {
    int ii = i - 393216;
    int l = ii >> 18, o = ii & 262143;
    int j = o & 7, fr = (o >> 3) & 15, fq = (o >> 7) & 3, ks = (o >> 9) & 3,
        rb = o >> 11;
    o2[ii] = f2h(w1[l * 262144 + (rb * 16 + fr) * 128 + ks * 32 + fq * 8 + j]);
  } else if (i < 3538944) {
    int ii = i - 1966080;
    int l = ii >> 18, o = ii & 262143;
    int j = o & 7, fr = (o >> 3) & 15, fq = (o >> 7) & 3, ks = (o >> 9) & 63,
        rb = o >> 15;
    o3[ii] = f2h(w2[l * 262144 + (rb * 16 + fr) * 2048 + ks * 32 + fq * 8 + j]);
  } else if (i < 3670016) {
    int j = i - 3538944; o4[j] = f2h(wih[j]);
  } else if (i < 3735552) {
    int j = i - 3670016; o5[j] = f2h(whh[j]);
  } else if (i < 3866624) {
    int j = i - 3735552; o6[j] = f2h(mwih[j]);
  } else if (i < 5963776) {
    int i2 = i - 3866624;
    int n = i2 >> 7, d = i2 & 127;
    float v = l0b[d] + data[n * 3 + 0] * l0w[d * 3 + 0]
                     + data[n * 3 + 1] * l0w[d * 3 + 1]
                     + data[n * 3 + 2] * l0w[d * 3 + 2];
    v = fmaxf(v, 0.0f);
    x[i2] = v;
    xb[i2] = f2h(v);
  }
}

// ---------------------------------------------------------------------------
// Fused transformer LAYER: block = (atom b, s-half), 256 threads, 4 waves.
// ---------------------------------------------------------------------------
__global__ __launch_bounds__(256, 2) void layer_kernel(
    const unsigned short* __restrict__ xbg,
    const unsigned short* __restrict__ wqkv, const float* __restrict__ bqkv,
    const unsigned short* __restrict__ wout, const float* __restrict__ bout,
    const float* __restrict__ ln1g, const float* __restrict__ ln1b,
    const unsigned short* __restrict__ w1, const float* __restrict__ b1,
    const unsigned short* __restrict__ w2, const float* __restrict__ b2,
    const float* __restrict__ ln2g, const float* __restrict__ ln2b,
    float* __restrict__ xio, unsigned short* __restrict__ xbo) {
  // shorts: Xs[0,8192) Ks[8192,16384) VT[16384,24576) Qs[24576,28672)
  __shared__ __align__(16) unsigned short SM[28672];
  __shared__ float psum[4][32], psq[4][32];
  __shared__ float2 stats[32];
  __shared__ __align__(16) uint4 zchunk;

  unsigned short* Xs = SM;             // x input -> P slots -> Hs buf0
  unsigned short* Ks = SM + 8192;      // K [s][feat] -> Hs buf1
  unsigned short* VT = SM + 16384;     // V^T [feat][s] -> AOs
  unsigned short* AOs = SM + 16384;    // AO [s][feat] 32x128
  unsigned short* Qs = SM + 24576;     // own-half Q [s][feat] 32x128 -> Xn
  unsigned short* Xn = SM + 24576;

  int tid = threadIdx.x, w = tid >> 6, lane = tid & 63;
  int b = blockIdx.x >> 1, half = blockIdx.x & 1;
  int r4 = lane >> 4, cs = lane & 15;
  int fr = lane & 15, fq = lane >> 4;

  if (tid == 0) zchunk = make_uint4(0u, 0u, 0u, 0u);

  // ---- phase 0: stage full x tile (rows 0..63) ----
#pragma unroll
  for (int i = 0; i < 4; i++) {
    int issue = w * 4 + i;
    int row = issue * 4 + r4;
    int g = cs ^ (row & 7);
    gl2lds16(xbg + (size_t)(row * 256 + b) * 128 + g * 8,
             (char*)Xs + issue * 1024);
  }
  // preload pass-Q weights (8 frags = 32 VGPR) while staging is in flight
  f16x8 wq[4][2];
#pragma unroll
  for (int ks = 0; ks < 4; ks++)
#pragma unroll
    for (int ni = 0; ni < 2; ni++)
      wq[ks][ni] = *(const f16x8*)(wqkv + (size_t)(w * 2 + ni) * 2048 +
                                   ks * 512 + fq * 128 + fr * 8);
  __syncthreads();

  // ---- phase 1: QKV, 3 passes, ONE barrier ----
  // Pass Q (SWAPPED: A=W, B=x): own 32 rows. D[qfeat][s] -> store Qs[s][qfeat]
  {
    f32x4 acc[2][2];
#pragma unroll
    for (int i = 0; i < 2; i++)
#pragma unroll
      for (int j = 0; j < 2; j++) acc[i][j] = (f32x4){0.f, 0.f, 0.f, 0.f};
#pragma unroll
    for (int ks = 0; ks < 4; ks++) {
      f16x8 bx[2];
#pragma unroll
      for (int mi2 = 0; mi2 < 2; mi2++) {
        int row = half * 32 + mi2 * 16 + fr;
        int kq = (ks * 4 + fq) ^ (row & 7);
        bx[mi2] = *(const f16x8*)(Xs + row * 128 + kq * 8);
      }
#pragma unroll
      for (int mi2 = 0; mi2 < 2; mi2++)
#pragma unroll
        for (int ni = 0; ni < 2; ni++)
          acc[mi2][ni] = __builtin_amdgcn_mfma_f32_16x16x32_f16(
              wq[ks][ni], bx[mi2], acc[mi2][ni], 0, 0, 0);
    }
#pragma unroll
    for (int ni = 0; ni < 2; ni++) {
      int fb = (w * 2 + ni) * 16 + fq * 4;
      float4 bv = *(const float4*)&bqkv[fb];
#pragma unroll
      for (int mi2 = 0; mi2 < 2; mi2++) {
        int srow = mi2 * 16 + fr;  // local 0..31
        *(uint2*)(Qs + srow * 128 + (((fb >> 3) ^ (srow & 7)) << 3) +
                  (fb & 7)) =
            pk4(acc[mi2][ni][0] + bv.x, acc[mi2][ni][1] + bv.y,
                acc[mi2][ni][2] + bv.z, acc[mi2][ni][3] + bv.w);
      }
    }
  }
  // Pass K (SWAPPED): full 64 rows. D[kfeat][s] -> store Ks[s][kfeat]
  {
    // preload all 8 K-weight frags
    f16x8 wk[4][2];
#pragma unroll
    for (int ks = 0; ks < 4; ks++)
#pragma unroll
      for (int ni = 0; ni < 2; ni++)
        wk[ks][ni] = *(const f16x8*)(wqkv + (size_t)(8 + w * 2 + ni) * 2048 +
                                     ks * 512 + fq * 128 + fr * 8);
    f32x4 acc[4][2];
#pragma unroll
    for (int i = 0; i < 4; i++)
#pragma unroll
      for (int j = 0; j < 2; j++) acc[i][j] = (f32x4){0.f, 0.f, 0.f, 0.f};
#pragma unroll
    for (int ks = 0; ks < 4; ks++) {
      f16x8 bx[4];
#pragma unroll
      for (int mi = 0; mi < 4; mi++) {
        int row = mi * 16 + fr;
        int kq = (ks * 4 + fq) ^ (row & 7);
        bx[mi] = *(const f16x8*)(Xs + row * 128 + kq * 8);
      }
#pragma unroll
      for (int mi = 0; mi < 4; mi++)
#pragma unroll
        for (int ni = 0; ni < 2; ni++)
          acc[mi][ni] = __builtin_amdgcn_mfma_f32_16x16x32_f16(
              wk[ks][ni], bx[mi], acc[mi][ni], 0, 0, 0);
    }
#pragma unroll
    for (int ni = 0; ni < 2; ni++) {
      int fb = (w * 2 + ni) * 16 + fq * 4;
      float4 bv = *(const float4*)&bqkv[128 + fb];
#pragma unroll
      for (int mi = 0; mi < 4; mi++) {
        int srow = mi * 16 + fr;
        *(uint2*)(Ks + srow * 128 + (((fb >> 3) ^ (srow & 7)) << 3) +
                  (fb & 7)) =
            pk4(acc[mi][ni][0] + bv.x, acc[mi][ni][1] + bv.y,
                acc[mi][ni][2] + bv.z, acc[mi][ni][3] + bv.w);
      }
    }
  }
  // Pass V (UNSWAPPED: A=x, B=W): D[s][vfeat] -> store VT[vfeat][s] packed
  {
    // preload all 8 V-weight frags
    f16x8 wv[4][2];
#pragma unroll
    for (int ks = 0; ks < 4; ks++)
#pragma unroll
      for (int ni = 0; ni < 2; ni++)
        wv[ks][ni] = *(const f16x8*)(wqkv + (size_t)(16 + w * 2 + ni) * 2048 +
                                     ks * 512 + fq * 128 + fr * 8);
    f32x4 acc[4][2];
#pragma unroll
    for (int i = 0; i < 4; i++)
#pragma unroll
      for (int j = 0; j < 2; j++) acc[i][j] = (f32x4){0.f, 0.f, 0.f, 0.f};
#pragma unroll
    for (int ks = 0; ks < 4; ks++) {
      f16x8 ax[4];
#pragma unroll
      for (int mi = 0; mi < 4; mi++) {
        int row = mi * 16 + fr;
        int kq = (ks * 4 + fq) ^ (row & 7);
        ax[mi] = *(const f16x8*)(Xs + row * 128 + kq * 8);
      }
#pragma unroll
      for (int mi = 0; mi < 4; mi++)
#pragma unroll
        for (int ni = 0; ni < 2; ni++)
          acc[mi][ni] = __builtin_amdgcn_mfma_f32_16x16x32_f16(
              ax[mi], wv[ks][ni], acc[mi][ni], 0, 0, 0);
    }
#pragma unroll
    for (int ni = 0; ni < 2; ni++) {
      int feat = (w * 2 + ni) * 16 + fr;
      float bv = bqkv[256 + feat];
#pragma unroll
      for (int mi = 0; mi < 4; mi++) {
        int sb = mi * 16 + fq * 4;
        *(uint2*)(VT + feat * 64 + (((sb >> 3) ^ (feat & 7)) << 3) +
                  (sb & 7)) =
            pk4(acc[mi][ni][0] + bv, acc[mi][ni][1] + bv,
                acc[mi][ni][2] + bv, acc[mi][ni][3] + bv);
      }
    }
  }
  // preload Wout frags (8 = 32 VGPR) -- consumed in phase 4, issued here so
  // L2 latency hides under the attention phase.
  f16x8 wo[4][2];
#pragma unroll
  for (int ks = 0; ks < 4; ks++)
#pragma unroll
    for (int ni = 0; ni < 2; ni++)
      wo[ks][ni] = *(const f16x8*)(wout + (size_t)(w * 2 + ni) * 2048 +
                                   ks * 512 + fq * 128 + fr * 8);
  __syncthreads();  // QKV published; Xs reads done -> Xs reusable as P slots

  // ---- attention: wave w -> heads {2w, 2w+1}, own 32 rows; P in Xs ----
  f32x4 po[2][2];
#pragma unroll
  for (int i = 0; i < 2; i++)
#pragma unroll
    for (int j = 0; j < 2; j++) po[i][j] = (f32x4){0.f, 0.f, 0.f, 0.f};
  {
    unsigned short* Pb = Xs + w * 2048;  // 4KB wave-private slot
#pragma unroll
    for (int hi = 0; hi < 2; hi++) {
      int h = w * 2 + hi;
      f16x8 afH[2], bfH[4];
#pragma unroll
      for (int mi2 = 0; mi2 < 2; mi2++) {
        int qrow = mi2 * 16 + fr;  // local 0..31
        const unsigned short* pa =
            (fq < 2) ? (Qs + qrow * 128 + (((h * 2 + fq) ^ (qrow & 7)) << 3))
                     : (const unsigned short*)&zchunk;
        afH[mi2] = *(const f16x8*)pa;
      }
#pragma unroll
      for (int ti = 0; ti < 4; ti++) {
        int trow = ti * 16 + fr;
        const unsigned short* pb =
            (fq < 2) ? (Ks + trow * 128 + (((h * 2 + fq) ^ (trow & 7)) << 3))
                     : (const unsigned short*)&zchunk;
        bfH[ti] = *(const f16x8*)pb;
      }
      f32x4 sc[2][4];
#pragma unroll
      for (int i = 0; i < 2; i++)
#pragma unroll
        for (int j = 0; j < 4; j++) sc[i][j] = (f32x4){0.f, 0.f, 0.f, 0.f};
#pragma unroll
      for (int mi2 = 0; mi2 < 2; mi2++)
#pragma unroll
        for (int ti = 0; ti < 4; ti++)
          sc[mi2][ti] = __builtin_amdgcn_mfma_f32_16x16x32_f16(
              afH[mi2], bfH[ti], sc[mi2][ti], 0, 0, 0);
#pragma unroll
      for (int mi2 = 0; mi2 < 2; mi2++) {
#pragma unroll
        for (int r = 0; r < 4; r++) {
          float m = -1e30f;
#pragma unroll
          for (int ti = 0; ti < 4; ti++) m = fmaxf(m, sc[mi2][ti][r]);
          m = fmaxf(m, __shfl_xor(m, 1, 64));
          m = fmaxf(m, __shfl_xor(m, 2, 64));
          m = fmaxf(m, __shfl_xor(m, 4, 64));
          m = fmaxf(m, __shfl_xor(m, 8, 64));
          m *= 0.25f;
          float ss = 0.f;
#pragma unroll
          for (int ti = 0; ti < 4; ti++) {
            float p = fexp(sc[mi2][ti][r] * 0.25f - m);
            sc[mi2][ti][r] = p;
            ss += p;
          }
          ss += __shfl_xor(ss, 1, 64);
          ss += __shfl_xor(ss, 2, 64);
          ss += __shfl_xor(ss, 4, 64);
          ss += __shfl_xor(ss, 8, 64);
          float inv = 1.f / ss;
          int prow = mi2 * 16 + fq * 4 + r;  // local 0..31
#pragma unroll
          for (int ti = 0; ti < 4; ti++) {
            int t = ti * 16 + fr;
            Pb[prow * 64 + (((t >> 3) ^ (prow & 7)) << 3) + (t & 7)] =
                f2h(sc[mi2][ti][r] * inv);
          }
        }
      }
      // PV SWAPPED: A=VT frag, B=P frag -> D[vfeat][s]
#pragma unroll
      for (int ks2 = 0; ks2 < 2; ks2++) {
        f16x8 bp[2], avt;
#pragma unroll
        for (int si2 = 0; si2 < 2; si2++) {
          int prow = si2 * 16 + fr;
          int kq = (ks2 * 4 + fq) ^ (prow & 7);
          bp[si2] = *(const f16x8*)(Pb + prow * 64 + kq * 8);
        }
        {
          int vrow = h * 16 + fr;
          int kq = (ks2 * 4 + fq) ^ (vrow & 7);
          avt = *(const f16x8*)(VT + vrow * 64 + kq * 8);
        }
#pragma unroll
        for (int si2 = 0; si2 < 2; si2++)
          po[hi][si2] = __builtin_amdgcn_mfma_f32_16x16x32_f16(
              avt, bp[si2], po[hi][si2], 0, 0, 0);
      }
    }
  }
  __syncthreads();  // all PV reads of VT done -> VT reusable as AOs
  // AO store: lane holds 4 consecutive vfeat at fixed s -> b64
#pragma unroll
  for (int hi = 0; hi < 2; hi++) {
    int fb = (w * 2 + hi) * 16 + fq * 4;
#pragma unroll
    for (int si2 = 0; si2 < 2; si2++) {
      int srow = si2 * 16 + fr;
      *(uint2*)(AOs + srow * 128 + (((fb >> 3) ^ (srow & 7)) << 3) +
                (fb & 7)) =
          pk4(po[hi][si2][0], po[hi][si2][1], po[hi][si2][2], po[hi][si2][3]);
    }
  }
  __syncthreads();  // AO published

  // ---- phase 4 (SWAPPED): v = x + ao @ Wout^T + bias ; LN1 -> Xn ----
  {
    f32x4 acc[2][2];
#pragma unroll
    for (int i = 0; i < 2; i++)
#pragma unroll
      for (int j = 0; j < 2; j++) acc[i][j] = (f32x4){0.f, 0.f, 0.f, 0.f};
#pragma unroll
    for (int ks = 0; ks < 4; ks++) {
      f16x8 bao[2];
#pragma unroll
      for (int mi2 = 0; mi2 < 2; mi2++) {
        int row = mi2 * 16 + fr;
        int kq = (ks * 4 + fq) ^ (row & 7);
        bao[mi2] = *(const f16x8*)(AOs + row * 128 + kq * 8);
      }
#pragma unroll
      for (int mi2 = 0; mi2 < 2; mi2++)
#pragma unroll
        for (int ni = 0; ni < 2; ni++)
          acc[mi2][ni] = __builtin_amdgcn_mfma_f32_16x16x32_f16(
              wo[ks][ni], bao[mi2], acc[mi2][ni], 0, 0, 0);
    }
    // lane: s = mi2*16+fr (local), feats = (w*2+ni)*16 + fq*4 + r
    float v4[2][2][4];  // [ni][mi2][r]
    float psA[2] = {0.f, 0.f}, psQ[2] = {0.f, 0.f};
#pragma unroll
    for (int ni = 0; ni < 2; ni++) {
      int fb = (w * 2 + ni) * 16 + fq * 4;
      float4 bv = *(const float4*)&bout[fb];
#pragma unroll
      for (int mi2 = 0; mi2 < 2; mi2++) {
        int rowg = half * 32 + mi2 * 16 + fr;
        float4 rs = *(const float4*)&xio[(size_t)(rowg * 256 + b) * 128 + fb];
        float t0 = acc[mi2][ni][0] + bv.x + rs.x;
        float t1 = acc[mi2][ni][1] + bv.y + rs.y;
        float t2 = acc[mi2][ni][2] + bv.z + rs.z;
        float t3 = acc[mi2][ni][3] + bv.w + rs.w;
        v4[ni][mi2][0] = t0; v4[ni][mi2][1] = t1;
        v4[ni][mi2][2] = t2; v4[ni][mi2][3] = t3;
        psA[mi2] += (t0 + t1) + (t2 + t3);
        psQ[mi2] += (t0 * t0 + t1 * t1) + (t2 * t2 + t3 * t3);
      }
    }
#pragma unroll
    for (int mi2 = 0; mi2 < 2; mi2++) {
      psA[mi2] += __shfl_xor(psA[mi2], 16, 64);
      psA[mi2] += __shfl_xor(psA[mi2], 32, 64);
      psQ[mi2] += __shfl_xor(psQ[mi2], 16, 64);
      psQ[mi2] += __shfl_xor(psQ[mi2], 32, 64);
    }
    if (fq == 0) {
#pragma unroll
      for (int mi2 = 0; mi2 < 2; mi2++) {
        psum[w][mi2 * 16 + fr] = psA[mi2];
        psq[w][mi2 * 16 + fr] = psQ[mi2];
      }
    }
    __syncthreads();  // A
    if (tid < 32) {
      float S = 0.f, Q = 0.f;
#pragma unroll
      for (int ww = 0; ww < 4; ww++) { S += psum[ww][tid]; Q += psq[ww][tid]; }
      float m = S * (1.f / 128.f);
      float var = Q * (1.f / 128.f) - m * m;
      stats[tid] = make_float2(m, rsqrtf(var + 1e-5f));
    }
    __syncthreads();  // B
#pragma unroll
    for (int ni = 0; ni < 2; ni++) {
      int fb = (w * 2 + ni) * 16 + fq * 4;
      float4 g4 = *(const float4*)&ln1g[fb];
      float4 b4 = *(const float4*)&ln1b[fb];
#pragma unroll
      for (int mi2 = 0; mi2 < 2; mi2++) {
        int srow = mi2 * 16 + fr;
        float2 st = stats[srow];
        float y0 = (v4[ni][mi2][0] - st.x) * st.y * g4.x + b4.x;
        float y1 = (v4[ni][mi2][1] - st.x) * st.y * g4.y + b4.y;
        float y2 = (v4[ni][mi2][2] - st.x) * st.y * g4.z + b4.z;
        float y3 = (v4[ni][mi2][3] - st.x) * st.y * g4.w + b4.w;
        *(uint2*)(Xn + srow * 128 + (((fb >> 3) ^ (srow & 7)) << 3) +
                  (fb & 7)) = pk4(y0, y1, y2, y3);
      }
    }
  }
  __syncthreads();  // C: LN1 out published; Xs+Ks dead -> Hs dbuf (2x16KB)

  // hoisted FFN x fragments (B-operand; local 32 rows)
  f16x8 xfragF[4][2];
#pragma unroll
  for (int ks = 0; ks < 4; ks++)
#pragma unroll
    for (int mi2 = 0; mi2 < 2; mi2++) {
      int rowl = mi2 * 16 + fr;
      int kq = (ks * 4 + fq) ^ (rowl & 7);
      xfragF[ks][mi2] = *(const f16x8*)(Xn + rowl * 128 + kq * 8);
    }

  // ---- FFN (SWAPPED): 8 chunks x 256 hidden. H stored [s][hcol] packed.
  f32x4 acc2[2][2];
#pragma unroll
  for (int i = 0; i < 2; i++)
#pragma unroll
    for (int j = 0; j < 2; j++) acc2[i][j] = (f32x4){0.f, 0.f, 0.f, 0.f};

  for (int c = 0; c < 8; c++) {
    unsigned short* Hcur = SM + (c & 1) * 8192;
    // preload full ff1 weight set for this chunk (16 frags = 64 VGPR)
    f16x8 aw1[4][4];
#pragma unroll
    for (int ks = 0; ks < 4; ks++)
#pragma unroll
      for (int ni = 0; ni < 4; ni++)
        aw1[ks][ni] = *(const f16x8*)(w1 + (size_t)(c * 16 + w * 4 + ni) *
                                              2048 +
                                      ks * 512 + fq * 128 + fr * 8);
    f32x4 acc1[2][4];
#pragma unroll
    for (int i = 0; i < 2; i++)
#pragma unroll
      for (int j = 0; j < 4; j++) acc1[i][j] = (f32x4){0.f, 0.f, 0.f, 0.f};
#pragma unroll
    for (int ks = 0; ks < 4; ks++)
#pragma unroll
      for (int mi2 = 0; mi2 < 2; mi2++)
#pragma unroll
        for (int ni = 0; ni < 4; ni++)
          acc1[mi2][ni] = __builtin_amdgcn_mfma_f32_16x16x32_f16(
              aw1[ks][ni], xfragF[ks][mi2], acc1[mi2][ni], 0, 0, 0);
#pragma unroll
    for (int ni = 0; ni < 4; ni++) {
      int hb = (w * 4 + ni) * 16 + fq * 4;  // 0..255
      float4 bv = *(const float4*)&b1[c * 256 + hb];
#pragma unroll
      for (int mi2 = 0; mi2 < 2; mi2++) {
        int srow = mi2 * 16 + fr;
        *(uint2*)(Hcur + srow * 256 + (((hb >> 3) ^ (srow & 7)) << 3) +
                  (hb & 7)) =
            pk4(fmaxf(acc1[mi2][ni][0] + bv.x, 0.f),
                fmaxf(acc1[mi2][ni][1] + bv.y, 0.f),
                fmaxf(acc1[mi2][ni][2] + bv.z, 0.f),
                fmaxf(acc1[mi2][ni][3] + bv.w, 0.f));
      }
    }
    // preload full ff2 weight set BEFORE the barrier (16 frags = 64 VGPR);
    // their ~200cy L2 latency hides under the barrier wait.
    f16x8 aw2[8][2];
#pragma unroll
    for (int ks2 = 0; ks2 < 8; ks2++)
#pragma unroll
      for (int ni = 0; ni < 2; ni++)
        aw2[ks2][ni] = *(const f16x8*)(w2 + (size_t)(w * 2 + ni) * 32768 +
                                       (c * 8 + ks2) * 512 + fq * 128 +
                                       fr * 8);
    __syncthreads();  // Hcur visible; dbuf -> 1 barrier/chunk
#pragma unroll
    for (int ks2 = 0; ks2 < 8; ks2++) {
      f16x8 bh[2];
#pragma unroll
      for (int mi2 = 0; mi2 < 2; mi2++) {
        int row = mi2 * 16 + fr;
        int kq = (ks2 * 4 + fq) ^ (row & 7);
        bh[mi2] = *(const f16x8*)(Hcur + row * 256 + kq * 8);
      }
#pragma unroll
      for (int mi2 = 0; mi2 < 2; mi2++)
#pragma unroll
        for (int ni = 0; ni < 2; ni++)
          acc2[mi2][ni] = __builtin_amdgcn_mfma_f32_16x16x32_f16(
              aw2[ks2][ni], bh[mi2], acc2[mi2][ni], 0, 0, 0);
    }
  }

  // ---- FFN epilogue: +b2 + residual (Xn), LN2, write global ----
  {
    float v4[2][2][4];  // [ni][mi2][r]
    float psA[2] = {0.f, 0.f}, psQ[2] = {0.f, 0.f};
#pragma unroll
    for (int ni = 0; ni < 2; ni++) {
      int fb = (w * 2 + ni) * 16 + fq * 4;
      float4 bv = *(const float4*)&b2[fb];
#pragma unroll
      for (int mi2 = 0; mi2 < 2; mi2++) {
        int srow = mi2 * 16 + fr;
        uint2 rz = *(const uint2*)(Xn + srow * 128 +
                                   (((fb >> 3) ^ (srow & 7)) << 3) + (fb & 7));
        float t0 = acc2[mi2][ni][0] + bv.x + hlo(rz.x);
        float t1 = acc2[mi2][ni][1] + bv.y + hhi(rz.x);
        float t2 = acc2[mi2][ni][2] + bv.z + hlo(rz.y);
        float t3 = acc2[mi2][ni][3] + bv.w + hhi(rz.y);
        v4[ni][mi2][0] = t0; v4[ni][mi2][1] = t1;
        v4[ni][mi2][2] = t2; v4[ni][mi2][3] = t3;
        psA[mi2] += (t0 + t1) + (t2 + t3);
        psQ[mi2] += (t0 * t0 + t1 * t1) + (t2 * t2 + t3 * t3);
      }
    }
#pragma unroll
    for (int mi2 = 0; mi2 < 2; mi2++) {
      psA[mi2] += __shfl_xor(psA[mi2], 16, 64);
      psA[mi2] += __shfl_xor(psA[mi2], 32, 64);
      psQ[mi2] += __shfl_xor(psQ[mi2], 16, 64);
      psQ[mi2] += __shfl_xor(psQ[mi2], 32, 64);
    }
    if (fq == 0) {
#pragma unroll
      for (int mi2 = 0; mi2 < 2; mi2++) {
        psum[w][mi2 * 16 + fr] = psA[mi2];
        psq[w][mi2 * 16 + fr] = psQ[mi2];
      }
    }
    __syncthreads();
    if (tid < 32) {
      float S = 0.f, Q = 0.f;
#pragma unroll
      for (int ww = 0; ww < 4; ww++) { S += psum[ww][tid]; Q += psq[ww][tid]; }
      float m = S * (1.f / 128.f);
      float var = Q * (1.f / 128.f) - m * m;
      stats[tid] = make_float2(m, rsqrtf(var + 1e-5f));
    }
    __syncthreads();
#pragma unroll
    for (int ni = 0; ni < 2; ni++) {
      int fb = (w * 2 + ni) * 16 + fq * 4;
      float4 g4 = *(const float4*)&ln2g[fb];
      float4 b4 = *(const float4*)&ln2b[fb];
#pragma unroll
      for (int mi2 = 0; mi2 < 2; mi2++) {
        int srow = mi2 * 16 + fr;
        float2 st = stats[srow];
        float y0 = (v4[ni][mi2][0] - st.x) * st.y * g4.x + b4.x;
        float y1 = (v4[ni][mi2][1] - st.x) * st.y * g4.y + b4.y;
        float y2 = (v4[ni][mi2][2] - st.x) * st.y * g4.z + b4.z;
        float y3 = (v4[ni][mi2][3] - st.x) * st.y * g4.w + b4.w;
        size_t o = (size_t)((half * 32 + srow) * 256 + b) * 128 + fb;
        *(float4*)&xio[o] = make_float4(y0, y1, y2, y3);
        *(uint2*)&xbo[o] = pk4(y0, y1, y2, y3);
      }
    }
  }
}

// ---------------------------------------------------------------------------
// Set2Set (6 steps) + memory LSTM + lin1 + lin3. One 512-thread block per
// segment. Full-row persistent gate weights (held at 512 thr), __expf,
// 4-way ILP r-phase.
// ---------------------------------------------------------------------------
__global__ __launch_bounds__(512, 1) void s2s_kernel(
    const unsigned short* __restrict__ xb,
    const unsigned short* __restrict__ wihh,
    const unsigned short* __restrict__ whhh,
    const float* __restrict__ bih, const float* __restrict__ bhh,
    const unsigned short* __restrict__ mwihh,
    const float* __restrict__ mbih, const float* __restrict__ mbhh,
    const float* __restrict__ l1w, const float* __restrict__ l1b,
    const float* __restrict__ l3w, const float* __restrict__ l3b,
    float* __restrict__ out) {
  __shared__ __align__(16) unsigned xl[256 * 65];
  __shared__ __align__(16) unsigned qu[128];
  __shared__ __align__(16) float cst[128];
  __shared__ __align__(16) float gates[512];
  __shared__ __align__(16) float red[256];
  __shared__ __align__(16) float aw[256];
  int s = blockIdx.x, t = threadIdx.x, lane = t & 63, w = t >> 6;

  uint4 wreg[32], ureg[16];
  {
    const uint4* wp = (const uint4*)(wihh + (size_t)t * 256);
#pragma unroll
    for (int i = 0; i < 32; i++) wreg[i] = wp[i];
    const uint4* up = (const uint4*)(whhh + (size_t)t * 128);
#pragma unroll
    for (int i = 0; i < 16; i++) ureg[i] = up[i];
  }

  const uint4* xs4 = (const uint4*)(xb + (size_t)s * 32768);
#pragma unroll
  for (int it = 0; it < 8; it++) {
    int f = it * 512 + t;
    uint4 v = xs4[f];
    int n = f >> 4, jc = (f & 15) * 4;
    unsigned* dst = xl + n * 65 + jc;
    dst[0] = v.x; dst[1] = v.y; dst[2] = v.z; dst[3] = v.w;
  }
  if (t < 128) cst[t] = 0.f;
  __syncthreads();

  const uint4* q4 = (const uint4*)qu;
  float bsum = bih[t] + bhh[t];

  for (int step = 0; step < 6; step++) {
    if (step > 0) {
      float a0 = 0.f, a1 = 0.f, a2 = 0.f, a3 = 0.f;
#pragma unroll
      for (int i = 0; i < 16; i++) {
        uint4 qv = q4[i];
        a0 = fdot2u(wreg[i].x, qv.x, a0);
        a1 = fdot2u(wreg[i].y, qv.y, a1);
        a2 = fdot2u(wreg[i].z, qv.z, a2);
        a3 = fdot2u(wreg[i].w, qv.w, a3);
        a0 = fdot2u(ureg[i].x, qv.x, a0);
        a1 = fdot2u(ureg[i].y, qv.y, a1);
        a2 = fdot2u(ureg[i].z, qv.z, a2);
        a3 = fdot2u(ureg[i].w, qv.w, a3);
      }
#pragma unroll
      for (int i = 16; i < 32; i++) {
        uint4 qv = q4[i];
        a0 = fdot2u(wreg[i].x, qv.x, a0);
        a1 = fdot2u(wreg[i].y, qv.y, a1);
        a2 = fdot2u(wreg[i].z, qv.z, a2);
        a3 = fdot2u(wreg[i].w, qv.w, a3);
      }
      gates[t] = bsum + ((a0 + a1) + (a2 + a3));
    } else {
      gates[t] = bsum;
    }
    __syncthreads();
    if (t < 128) {
      float ig = sigf(gates[t]), fg = sigf(gates[128 + t]);
      float gg = ftanh(gates[256 + t]), og = sigf(gates[384 + t]);
      float cn = fg * cst[t] + ig * gg;
      cst[t] = cn;
      float hn = og * ftanh(cn);
      float hp = __shfl_xor(hn, 1, 64);
      if ((t & 1) == 0) qu[t >> 1] = packh(hn, hp);
    }
    __syncthreads();
    if (step > 0) {
      int n = t >> 1, p = t & 1;
      const unsigned* xr = xl + n * 65 + p * 32;
      float e0 = 0.f, e1 = 0.f;
#pragma unroll 8
      for (int i = 0; i < 32; i += 2) {
        e0 = fdot2u(xr[i], qu[p * 32 + i], e0);
        e1 = fdot2u(xr[i + 1], qu[p * 32 + i + 1], e1);
      }
      float e = e0 + e1;
      e += __shfl_xor(e, 1, 64);
      if (p == 0) red[n] = e;
      __syncthreads();
      float v0 = red[lane], v1 = red[64 + lane];
      float v2 = red[128 + lane], v3 = red[192 + lane];
      float m = fmaxf(fmaxf(v0, v1), fmaxf(v2, v3));
#pragma unroll
      for (int d = 1; d < 64; d <<= 1) m = fmaxf(m, __shfl_xor(m, d, 64));
      float p0 = fexp(v0 - m), p1 = fexp(v1 - m);
      float p2 = fexp(v2 - m), p3 = fexp(v3 - m);
      float ss = p0 + p1 + p2 + p3;
#pragma unroll
      for (int d = 1; d < 64; d <<= 1) ss += __shfl_xor(ss, d, 64);
      float Sinv = 1.f / ss;
      if (w == 0) {
        aw[lane] = p0 * Sinv; aw[64 + lane] = p1 * Sinv;
        aw[128 + lane] = p2 * Sinv; aw[192 + lane] = p3 * Sinv;
      }
    } else {
      if (t < 256) aw[t] = 1.f / 256.f;
    }
    __syncthreads();
    {
      int d = t & 127, grp = t >> 7;
      const unsigned* xc = xl + grp * 64 * 65 + (d >> 1);
      int hi = d & 1;
      const float* ap = aw + grp * 64;
      // 4 independent accumulators: chain 16, loads 4-deep in flight
      float r0 = 0.f, r1 = 0.f, r2 = 0.f, r3 = 0.f;
#pragma unroll 4
      for (int n2 = 0; n2 < 64; n2 += 4) {
        unsigned u0 = xc[n2 * 65], u1 = xc[(n2 + 1) * 65];
        unsigned u2 = xc[(n2 + 2) * 65], u3 = xc[(n2 + 3) * 65];
        r0 += ap[n2] * (hi ? hhi(u0) : hlo(u0));
        r1 += ap[n2 + 1] * (hi ? hhi(u1) : hlo(u1));
        r2 += ap[n2 + 2] * (hi ? hhi(u2) : hlo(u2));
        r3 += ap[n2 + 3] * (hi ? hhi(u3) : hlo(u3));
      }
      gates[t] = (r0 + r1) + (r2 + r3);
    }
    __syncthreads();
    if (t < 128) {
      float rd = gates[t] + gates[128 + t] + gates[256 + t] + gates[384 + t];
      float rp = __shfl_xor(rd, 1, 64);
      if ((t & 1) == 0) qu[64 + (t >> 1)] = packh(rd, rp);
    }
    __syncthreads();
  }
  {
    float a0 = 0.f, a1 = 0.f, a2 = 0.f, a3 = 0.f;
    const uint4* mp = (const uint4*)(mwihh + (size_t)t * 256);
#pragma unroll 8
    for (int i = 0; i < 32; i++) {
      uint4 wv = mp[i], qv = q4[i];
      a0 = fdot2u(wv.x, qv.x, a0);
      a1 = fdot2u(wv.y, qv.y, a1);
      a2 = fdot2u(wv.z, qv.z, a2);
      a3 = fdot2u(wv.w, qv.w, a3);
    }
    gates[t] = mbih[t] + mbhh[t] + ((a0 + a1) + (a2 + a3));
  }
  __syncthreads();
  if (t < 128) {
    float ig = sigf(gates[t]);
    float gg = ftanh(gates[256 + t]);
    float og = sigf(gates[384 + t]);
    float cx = ig * gg;
    float hx = og * ftanh(cx);
    cst[t] = hx;
    out[64 + s * 128 + t] = hx;
    out[64 + 8192 + s * 128 + t] = cx;
  }
  __syncthreads();
  if (t < 128) {
    float acc = l1b[t];
    const float4* w4 = (const float4*)(l1w + (size_t)t * 128);
    const float4* h4 = (const float4*)cst;
#pragma unroll 8
    for (int k = 0; k < 32; k++) {
      float4 a = w4[k], b = h4[k];
      acc += a.x * b.x + a.y * b.y + a.z * b.z + a.w * b.w;
    }
    red[t] = fmaxf(acc, 0.f) * l3w[t];
  } else if (t < 256) {
    red[t] = 0.f;
  }
  __syncthreads();
  for (int off = 128; off; off >>= 1) {
    if (t < off) red[t] += red[t + off];
    __syncthreads();
  }
  if (t == 0) out[s] = red[0] + l3b[0];
}

// ---------------------------------------------------------------------------
extern "C" void kernel_launch(void* const* d_in, const int* in_sizes, int n_in,
                              void* d_out, int out_size, void* d_ws,
                              size_t ws_size, hipStream_t stream) {
  const float* data       = (const float*)d_in[0];
  const float* lin0_w     = (const float*)d_in[1];
  const float* lin0_b     = (const float*)d_in[2];
  const float* attn_in_w  = (const float*)d_in[3];
  const float* attn_in_b  = (const float*)d_in[4];
  const float* attn_out_w = (const float*)d_in[5];
  const float* attn_out_b = (const float*)d_in[6];
  const float* ln1_g      = (const float*)d_in[7];
  const float* ln1_b      = (const float*)d_in[8];
  const float* ff_w1      = (const float*)d_in[9];
  const float* ff_b1      = (const float*)d_in[10];
  const float* ff_w2      = (const float*)d_in[11];
  const float* ff_b2      = (const float*)d_in[12];
  const float* ln2_g      = (const float*)d_in[13];
  const float* ln2_b      = (const float*)d_in[14];
  const float* s2s_wih    = (const float*)d_in[15];
  const float* s2s_whh    = (const float*)d_in[16];
  const float* s2s_bih    = (const float*)d_in[17];
  const float* s2s_bhh    = (const float*)d_in[18];
  const float* mem_wih    = (const float*)d_in[19];
  const float* mem_bih    = (const float*)d_in[21];
  const float* mem_bhh    = (const float*)d_in[22];
  const float* lin1_w     = (const float*)d_in[23];
  const float* lin1_b     = (const float*)d_in[24];
  const float* lin3_w     = (const float*)d_in[25];
  const float* lin3_b     = (const float*)d_in[26];
  float* out = (float*)d_out;

  char* p = (char*)d_ws;
  float* x = (float*)p;                      p += (size_t)16384 * 128 * 4;
  unsigned short* xb = (unsigned short*)p;   p += (size_t)16384 * 128 * 2;
  unsigned short* wqkv = (unsigned short*)p; p += (size_t)294912 * 2;
  unsigned short* wout = (unsigned short*)p; p += (size_t)98304 * 2;
  unsigned short* w1h = (unsigned short*)p;  p += (size_t)1572864 * 2;
  unsigned short* w2h = (unsigned short*)p;  p += (size_t)1572864 * 2;
  unsigned short* wihh = (unsigned short*)p; p += (size_t)131072 * 2;
  unsigned short* whhh = (unsigned short*)p; p += (size_t)65536 * 2;
  unsigned short* mwihh = (unsigned short*)p; p += (size_t)131072 * 2;

  // merged weight-convert + lin0: 3866624 + 2097152 = 5963776 elems
  prep_kernel<<<23296, 256, 0, stream>>>(
      attn_in_w, attn_out_w, ff_w1, ff_w2, s2s_wih, s2s_whh, mem_wih,
      wqkv, wout, w1h, w2h, wihh, whhh, mwihh,
      data, lin0_w, lin0_b, x, xb);

  for (int l = 0; l < 6; l++) {
    layer_kernel<<<512, 256, 0, stream>>>(
        xb, wqkv + (size_t)l * 49152, attn_in_b + l * 384,
        wout + (size_t)l * 16384, attn_out_b + l * 128,
        ln1_g + l * 128, ln1_b + l * 128,
        w1h + (size_t)l * 262144, ff_b1 + l * 2048,
        w2h + (size_t)l * 262144, ff_b2 + l * 128,
        ln2_g + l * 128, ln2_b + l * 128, x, xb);
  }

  s2s_kernel<<<64, 512, 0, stream>>>(
      xb, wihh, whhh, s2s_bih, s2s_bhh,
      mwihh, mem_bih, mem_bhh, lin1_w, lin1_b, lin3_w, lin3_b, out);
}